// Round 22
// baseline (151.231 us; speedup 1.0000x reference)
//
#include <hip/hip_runtime.h>
#include <hip/hip_fp16.h>
#include <math.h>

#define NN 50000
#define NE 1600000
#define NBKT 196         // ceil(50000 / 256)
#define BKT_SHIFT 8      // 256 nodes per bucket
#define BCAP 16384       // fixed bucket capacity (mean 8163, sigma ~90)
#define SCAP 12288       // sortB LDS staging capacity (45 sigma above mean)

typedef unsigned int u32;
typedef unsigned long long u64;
typedef _Float16 f16x8 __attribute__((ext_vector_type(8)));
typedef _Float16 f16x4 __attribute__((ext_vector_type(4)));
typedef float f32x4 __attribute__((ext_vector_type(4)));

// fast celu: __expf is the HW v_exp path; abs err ~1e-7, threshold is 1.97e-2
__device__ __forceinline__ float celu_fast(float v) {
    return v > 0.0f ? v : __expf(v) - 1.0f;
}

// swizzled LDS layout for 128B-row f16 tiles: 8B chunks (4 f16),
// chunk c4 of row r -> half-index r*64 + (c4 ^ ((r&7)<<1))*4
__device__ __forceinline__ __half* hptr(__half* base, int row, int c4) {
    return base + (row << 6) + ((c4 ^ ((row & 7) << 1)) << 2);
}

// ======================= binA + prep fused (512 threads) =======================
__global__ __launch_bounds__(512) void binA_prep_kernel(
    const int* __restrict__ ei, u32* __restrict__ gcur, u32* __restrict__ sd1,
    uint4* __restrict__ aggr4,
    const float* __restrict__ x, const float* __restrict__ pos,
    float* __restrict__ xp,
    const float* __restrict__ fw1, const float* __restrict__ fw2,
    const float* __restrict__ gw1, const float* __restrict__ gw2,
    __half* __restrict__ w1t, __half* __restrict__ w2t,
    __half* __restrict__ g1t, __half* __restrict__ g2t,
    float* __restrict__ w1x)
{
    const int tid = threadIdx.x;
    const int b = blockIdx.x;
    if (b == 196) {
        for (int i = tid; i < 4096; i += 512) {
            const int n = i >> 6, k = i & 63;
            w2t[i] = __float2half(fw2[k * 64 + n]);
            g1t[i] = __float2half(gw1[k * 64 + n]);
            g2t[i] = __float2half(gw2[k * 64 + n]);
        }
        if (tid < 512) {
            const int n = tid >> 3, k = tid & 7;
            w1t[tid] = (k < 6) ? __float2half(fw1[k * 64 + n]) : __half(0.0f);
        }
        if (tid < 192) {
            const int c = tid >> 6, ch = tid & 63;
            w1x[tid] = gw1[(64 + c) * 64 + ch];
        }
        return;
    }

    // prep side-work: zero aggr slice + xp build
    for (int idx = b * 512 + tid; idx < NN * 64 / 4; idx += 196 * 512)
        aggr4[idx] = make_uint4(0u, 0u, 0u, 0u);
    {
        const int n = b * 512 + tid;
        if (n < NN) {
            float4 a, p;
            a.x = x[n * 3 + 0]; a.y = x[n * 3 + 1]; a.z = x[n * 3 + 2]; a.w = 0.f;
            p.x = pos[n * 3 + 0]; p.y = pos[n * 3 + 1]; p.z = pos[n * 3 + 2]; p.w = 0.f;
            *(float4*)&xp[n * 8 + 0] = a;
            *(float4*)&xp[n * 8 + 4] = p;
        }
    }

    // bin 8192 edges via LDS staging
    __shared__ u32 s_hist[NBKT];
    __shared__ u32 s_res[NBKT];
    __shared__ u32 s_lofs[NBKT];
    __shared__ u32 s_cur[NBKT];
    __shared__ u32 s_scan[256];
    __shared__ u32 s_stage[8192];   // 32 KiB

    if (tid < NBKT) { s_hist[tid] = 0u; s_cur[tid] = 0u; }
    __syncthreads();

    const int e0 = b * 8192 + tid * 16;
    const bool valid = (e0 < NE);
    u32 ed[16];
    if (valid) {
        const int4* sp = (const int4*)&ei[e0];
        const int4* dp = (const int4*)&ei[NE + e0];
#pragma unroll
        for (int q = 0; q < 4; ++q) {
            int4 s4 = sp[q];
            int4 d4 = dp[q];
            ed[q * 4 + 0] = ((u32)d4.x << 16) | (u32)s4.x;
            ed[q * 4 + 1] = ((u32)d4.y << 16) | (u32)s4.y;
            ed[q * 4 + 2] = ((u32)d4.z << 16) | (u32)s4.z;
            ed[q * 4 + 3] = ((u32)d4.w << 16) | (u32)s4.w;
        }
#pragma unroll
        for (int q = 0; q < 16; ++q)
            atomicAdd(&s_hist[ed[q] >> 24], 1u);
    }
    __syncthreads();
    if (tid < NBKT && s_hist[tid]) s_res[tid] = atomicAdd(&gcur[tid], s_hist[tid]);
    if (tid < 256) s_scan[tid] = (tid < NBKT) ? s_hist[tid] : 0u;
    __syncthreads();
    for (int d = 1; d < 256; d <<= 1) {
        u32 t = 0u;
        if (tid < 256 && tid >= d) t = s_scan[tid - d];
        __syncthreads();
        if (tid < 256) s_scan[tid] += t;
        __syncthreads();
    }
    if (tid < NBKT) s_lofs[tid] = s_scan[tid] - s_hist[tid];
    __syncthreads();
    if (valid) {
#pragma unroll
        for (int q = 0; q < 16; ++q) {
            const u32 bb = ed[q] >> 24;
            const u32 r = atomicAdd(&s_cur[bb], 1u);
            s_stage[s_lofs[bb] + r] = ed[q];
        }
    }
    __syncthreads();
    const int wv = tid >> 6;
    const int lane = tid & 63;
    for (int bk = wv; bk < NBKT; bk += 8) {
        const u32 cnt = s_hist[bk];
        if (!cnt) continue;
        const u32 lo = s_lofs[bk];
        const u32 gres = s_res[bk];
        for (u32 j = (u32)lane; j < cnt; j += 64) {
            const u32 p = gres + j;
            if (p < BCAP) sd1[(u32)bk * BCAP + p] = s_stage[lo + j];
        }
    }
}

// counting sort within each bucket (256 bins), 512 threads, LDS-staged output
__global__ __launch_bounds__(512) void sortB_kernel(const u32* __restrict__ sd1,
                                                    const u32* __restrict__ gcur,
                                                    u32* __restrict__ sd2) {
    __shared__ u32 s_scan[256];
    __shared__ u32 s_cnt[256];
    __shared__ u32 s_pos[256];
    __shared__ u32 s_stage[SCAP];   // 48 KiB
    const int tid = threadIdx.x;
    const int b = blockIdx.x;

    if (tid < 256) s_scan[tid] = (tid < NBKT) ? gcur[tid] : 0u;
    __syncthreads();
    for (int d = 1; d < 256; d <<= 1) {
        u32 t = 0u;
        if (tid < 256 && tid >= d) t = s_scan[tid - d];
        __syncthreads();
        if (tid < 256) s_scan[tid] += t;
        __syncthreads();
    }
    u32 cnt = gcur[b];
    if (cnt > BCAP) cnt = BCAP;
    const u32 outbase = s_scan[b] - cnt;
    const u32 src = (u32)b * BCAP;

    if (tid < 256) s_cnt[tid] = 0u;
    __syncthreads();
    for (u32 j = tid; j < cnt; j += 512)
        atomicAdd(&s_cnt[(sd1[src + j] >> 16) & 255u], 1u);
    __syncthreads();
    if (tid < 256) s_pos[tid] = s_cnt[tid];
    __syncthreads();
    for (int d = 1; d < 256; d <<= 1) {
        u32 t = 0u;
        if (tid < 256 && tid >= d) t = s_pos[tid - d];
        __syncthreads();
        if (tid < 256) s_pos[tid] += t;
        __syncthreads();
    }
    if (tid < 256) s_pos[tid] -= s_cnt[tid];
    __syncthreads();

    if (cnt <= SCAP) {
        for (u32 j = tid; j < cnt; j += 512) {
            const u32 sd = sd1[src + j];
            const u32 dl = (sd >> 16) & 255u;
            const u32 r = atomicAdd(&s_pos[dl], 1u);
            s_stage[r] = sd;
        }
        __syncthreads();
        for (u32 j = tid; j < cnt; j += 512)
            sd2[outbase + j] = s_stage[j];
    } else {
        for (u32 j = tid; j < cnt; j += 512) {
            const u32 sd = sd1[src + j];
            const u32 dl = (sd >> 16) & 255u;
            const u32 r = atomicAdd(&s_pos[dl], 1u);
            sd2[outbase + r] = sd;
        }
    }
}

// ======================= fused edge+gather kernel: 512 threads, 256 edges =======================
// 8 waves per block; each wave owns 32 edge rows (2 MFMA row-groups).
// Same LDS (39.4 KB -> 4 blocks/CU) but 8 waves/block -> 32 waves/CU occupancy.
__global__ __launch_bounds__(512, 8) void edge_fused_kernel(
    const float* __restrict__ xp,
    const u32* __restrict__ sdb,
    const __half* __restrict__ w1t, const float* __restrict__ fb1,
    const __half* __restrict__ w2t, const float* __restrict__ fb2,
    u32* __restrict__ aggr)
{
    __shared__ __align__(16) __half s_in[256 * 8];   // 4 KiB
    __shared__ __align__(16) __half s_h[256 * 64];   // 32 KiB, swizzled
    __shared__ u32 s_d[256];
    __shared__ u32 s_start[257];
    __shared__ u32 s_nseg;

    const int tid = threadIdx.x;
    // bijective XCD-chunked swizzle (nwg=6250: q=781, r=2)
    const int xcd = blockIdx.x & 7;
    const int idx = blockIdx.x >> 3;
    const int ebid = (xcd < 2) ? xcd * 782 + idx : 2 * 782 + (xcd - 2) * 781 + idx;

    // staging: first 256 threads handle one edge each
    if (tid < 256) {
        const int i = ebid * 256 + tid;
        const u32 w = sdb[i];
        const int s = (int)(w & 0xFFFFu);
        const int d = (int)(w >> 16);
        s_d[tid] = (u32)d;
        const float4* xp4 = (const float4*)xp;
        float4 axs = xp4[s * 2];
        float4 aps = xp4[s * 2 + 1];
        float4 apd = xp4[d * 2 + 1];
        union { uint4 u; __half2 h2[4]; } pk;
        pk.h2[0] = __floats2half2_rn(axs.x, axs.y);
        pk.h2[1] = __floats2half2_rn(axs.z, aps.x - apd.x);
        pk.h2[2] = __floats2half2_rn(aps.y - apd.y, aps.z - apd.z);
        pk.h2[3] = __floats2half2_rn(0.f, 0.f);
        *(uint4*)&s_in[tid * 8] = pk.u;
    }
    __syncthreads();   // s_in + s_d ready

    const int l = tid & 63;
    const int wv = tid >> 6;       // 0..7
    const int rbase = wv << 5;     // wave's 32-edge base row
    const int lrow = l & 15;
    const int lhi = l >> 4;

    // ---- layer 1 on MFMA (2 row-groups per wave) ----
    const f16x8 zero8 = {};
    f16x8 b1f[2];
#pragma unroll
    for (int nt = 0; nt < 2; ++nt) {
        b1f[nt] = zero8;
        if (lhi == 0)
            b1f[nt] = *(const f16x8*)&s_in[(rbase + nt * 16 + lrow) * 8];
    }

#pragma unroll
    for (int mt = 0; mt < 4; ++mt) {
        f16x8 a = zero8;
        if (lhi == 0) a = *(const f16x8*)&w1t[(mt * 16 + lrow) * 8];
        const f32x4 c0 = *(const f32x4*)&fb1[mt * 16 + lhi * 4];
#pragma unroll
        for (int nt = 0; nt < 2; ++nt) {
            f32x4 z = __builtin_amdgcn_mfma_f32_16x16x32_f16(a, b1f[nt], c0, 0, 0, 0);
            const int row = rbase + nt * 16 + lrow;
            union { uint2 u; __half2 h2[2]; } pk;
            pk.h2[0] = __floats2half2_rn(celu_fast(z[0]), celu_fast(z[1]));
            pk.h2[1] = __floats2half2_rn(celu_fast(z[2]), celu_fast(z[3]));
            *(uint2*)hptr(s_h, row, mt * 4 + lhi) = pk.u;
        }
    }

    // wave 0: segment head-scan over sorted dst -> s_start[0..nseg]
    if (tid < 64) {
        u32 base = 0;
        for (int c = 0; c < 4; ++c) {
            const int t = c * 64 + tid;
            const bool head = (t == 0) || (s_d[t] != s_d[t - 1]);
            const u64 m = __ballot(head);
            const u32 pos0 = base + (u32)__popcll(m & ((1ull << tid) - 1ull));
            if (head) s_start[pos0] = (u32)t;
            base += (u32)__popcll(m);
        }
        if (tid == 0) { s_nseg = base; s_start[base] = 256u; }
    }

    // L2 weight fragments + bias (global, L2-cached)
    f16x8 afrag[4][2];
#pragma unroll
    for (int at = 0; at < 4; ++at)
#pragma unroll
        for (int kt = 0; kt < 2; ++kt)
            afrag[at][kt] = *(const f16x8*)(w2t + ((at * 16 + lrow) << 6) + kt * 32 + (lhi << 3));
    f32x4 bias2[4];
#pragma unroll
    for (int at = 0; at < 4; ++at)
        bias2[at] = *(const f32x4*)(fb2 + at * 16 + (lhi << 2));

    __syncthreads();   // s_h (h values) ready

    // ---- layer 2 on MFMA, in-place writeback (2 row-groups per wave) ----
#pragma unroll
    for (int g = 0; g < 2; ++g) {
        const int rb = rbase + g * 16 + lrow;
        f32x4 acc[4];
#pragma unroll
        for (int at = 0; at < 4; ++at) acc[at] = bias2[at];
#pragma unroll
        for (int kt = 0; kt < 2; ++kt) {
            f16x8 b = *(const f16x8*)hptr(s_h, rb, (kt * 4 + lhi) * 2);
            acc[0] = __builtin_amdgcn_mfma_f32_16x16x32_f16(afrag[0][kt], b, acc[0], 0, 0, 0);
            acc[1] = __builtin_amdgcn_mfma_f32_16x16x32_f16(afrag[1][kt], b, acc[1], 0, 0, 0);
            acc[2] = __builtin_amdgcn_mfma_f32_16x16x32_f16(afrag[2][kt], b, acc[2], 0, 0, 0);
            acc[3] = __builtin_amdgcn_mfma_f32_16x16x32_f16(afrag[3][kt], b, acc[3], 0, 0, 0);
        }
#pragma unroll
        for (int at = 0; at < 4; ++at) {
            union { uint2 u; __half2 h2[2]; } pk;
            pk.h2[0] = __floats2half2_rn(acc[at][0], acc[at][1]);
            pk.h2[1] = __floats2half2_rn(acc[at][2], acc[at][3]);
            *(uint2*)hptr(s_h, rb, at * 4 + lhi) = pk.u;
        }
    }
    __syncthreads();   // messages + segment table ready

    // ---- segmented max-reduce: 16 half-waves, 2 rows/iter ----
    const int hw = tid >> 5;       // 0..15
    const int lane2 = tid & 31;
    const int sub = lane2 >> 4;
    const int c8 = lane2 & 15;
    const u32 nseg = s_nseg;
    for (u32 j = (u32)hw; j < nseg; j += 16) {
        const u32 lo = s_start[j];
        const u32 hi = s_start[j + 1];
        const u32 node = s_d[lo];
        f16x4 m = {};
        for (u32 r0 = lo; r0 < hi; r0 += 2) {
            const u32 r = r0 + (u32)sub;
            if (r < hi) {
                f16x4 v = *(const f16x4*)hptr(s_h, (int)r, c8);
                m = __builtin_elementwise_max(m, v);
            }
        }
        union { f16x4 v; int w2[2]; } a, b;
        a.v = m;
        b.w2[0] = __shfl_down(a.w2[0], 16, 32);
        b.w2[1] = __shfl_down(a.w2[1], 16, 32);
        f16x4 mm = __builtin_elementwise_max(a.v, b.v);
        if (sub == 0) {
            if (lo > 0u && hi < 256u) {
                float4 st;
                st.x = fmaxf((float)mm[0], 0.f);
                st.y = fmaxf((float)mm[1], 0.f);
                st.z = fmaxf((float)mm[2], 0.f);
                st.w = fmaxf((float)mm[3], 0.f);
                *(float4*)((float*)aggr + (size_t)node * 64 + c8 * 4) = st;
            } else {
                u32* arow = aggr + (size_t)node * 64 + c8 * 4;
#pragma unroll
                for (int t = 0; t < 4; ++t) {
                    float f = (float)mm[t];
                    if (f > 0.f) atomicMax(&arow[t], __float_as_uint(f));
                }
            }
        }
    }
}

// ======================= node update MLP on MFMA: 256 threads, 128 nodes =======================
__global__ __launch_bounds__(256) void node_mfma_kernel(
    const float* __restrict__ xp,
    float* io,   // d_out: aggr in, final out
    const __half* __restrict__ g1t, const float* __restrict__ w1x,
    const float* __restrict__ gb1,
    const __half* __restrict__ g2t, const float* __restrict__ gb2)
{
    __shared__ __align__(16) __half s_a[128 * 64];
    __shared__ __align__(16) __half s_u[128 * 64];
    __shared__ __align__(16) float s_x[128 * 4];

    const int tid = threadIdx.x;
    const int n0 = blockIdx.x * 128;

#pragma unroll
    for (int it = 0; it < 8; ++it) {
        const int idx = it * 256 + tid;
        const int row = idx >> 4, c8 = idx & 15;
        const int g = n0 + row;
        float4 v = make_float4(0.f, 0.f, 0.f, 0.f);
        if (g < NN) v = *(const float4*)&io[(size_t)g * 64 + c8 * 4];
        union { uint2 u; __half2 h2[2]; } pk;
        pk.h2[0] = __floats2half2_rn(v.x, v.y);
        pk.h2[1] = __floats2half2_rn(v.z, v.w);
        *(uint2*)hptr(s_a, row, c8) = pk.u;
    }
    if (tid < 128) {
        const int g = n0 + tid;
        float4 a = make_float4(0.f, 0.f, 0.f, 0.f);
        if (g < NN) a = *(const float4*)&xp[(size_t)g * 8];
        *(float4*)&s_x[tid * 4] = a;
    }
    __syncthreads();

    const int l = tid & 63;
    const int wv = tid >> 6;           // 0..3, each wave owns 32 rows
    const int lrow = l & 15;
    const int lhi = l >> 4;

    f16x8 a1[4][2], a2[4][2];
    f32x4 bias1[4], bias2[4];
    f32x4 wx0[4], wx1[4], wx2[4];
#pragma unroll
    for (int at = 0; at < 4; ++at) {
#pragma unroll
        for (int kt = 0; kt < 2; ++kt) {
            const int off = ((at * 16 + lrow) << 6) + kt * 32 + (lhi << 3);
            a1[at][kt] = *(const f16x8*)(g1t + off);
            a2[at][kt] = *(const f16x8*)(g2t + off);
        }
        bias1[at] = *(const f32x4*)&gb1[at * 16 + lhi * 4];
        bias2[at] = *(const f32x4*)&gb2[at * 16 + lhi * 4];
        const int ch = at * 16 + lhi * 4;
        wx0[at] = *(const f32x4*)&w1x[0 * 64 + ch];
        wx1[at] = *(const f32x4*)&w1x[1 * 64 + ch];
        wx2[at] = *(const f32x4*)&w1x[2 * 64 + ch];
    }

#pragma unroll
    for (int g = 0; g < 2; ++g) {
        const int rb = wv * 32 + g * 16 + lrow;
        f32x4 acc[4];
#pragma unroll
        for (int at = 0; at < 4; ++at) acc[at] = bias1[at];
#pragma unroll
        for (int kt = 0; kt < 2; ++kt) {
            f16x8 b = *(const f16x8*)hptr(s_a, rb, (kt * 4 + lhi) * 2);
            acc[0] = __builtin_amdgcn_mfma_f32_16x16x32_f16(a1[0][kt], b, acc[0], 0, 0, 0);
            acc[1] = __builtin_amdgcn_mfma_f32_16x16x32_f16(a1[1][kt], b, acc[1], 0, 0, 0);
            acc[2] = __builtin_amdgcn_mfma_f32_16x16x32_f16(a1[2][kt], b, acc[2], 0, 0, 0);
            acc[3] = __builtin_amdgcn_mfma_f32_16x16x32_f16(a1[3][kt], b, acc[3], 0, 0, 0);
        }
        const float x0 = s_x[rb * 4 + 0];
        const float x1 = s_x[rb * 4 + 1];
        const float x2 = s_x[rb * 4 + 2];
#pragma unroll
        for (int at = 0; at < 4; ++at) {
            f32x4 z = acc[at];
#pragma unroll
            for (int t = 0; t < 4; ++t)
                z[t] = fmaf(x0, wx0[at][t], fmaf(x1, wx1[at][t], fmaf(x2, wx2[at][t], z[t])));
            union { uint2 u; __half2 h2[2]; } pk;
            pk.h2[0] = __floats2half2_rn(celu_fast(z[0]), celu_fast(z[1]));
            pk.h2[1] = __floats2half2_rn(celu_fast(z[2]), celu_fast(z[3]));
            *(uint2*)hptr(s_u, rb, at * 4 + lhi) = pk.u;
        }
    }
    __syncthreads();

#pragma unroll
    for (int g = 0; g < 2; ++g) {
        const int rb = wv * 32 + g * 16 + lrow;
        const int node = n0 + rb;
        f32x4 acc[4];
#pragma unroll
        for (int at = 0; at < 4; ++at) acc[at] = bias2[at];
#pragma unroll
        for (int kt = 0; kt < 2; ++kt) {
            f16x8 b = *(const f16x8*)hptr(s_u, rb, (kt * 4 + lhi) * 2);
            acc[0] = __builtin_amdgcn_mfma_f32_16x16x32_f16(a2[0][kt], b, acc[0], 0, 0, 0);
            acc[1] = __builtin_amdgcn_mfma_f32_16x16x32_f16(a2[1][kt], b, acc[1], 0, 0, 0);
            acc[2] = __builtin_amdgcn_mfma_f32_16x16x32_f16(a2[2][kt], b, acc[2], 0, 0, 0);
            acc[3] = __builtin_amdgcn_mfma_f32_16x16x32_f16(a2[3][kt], b, acc[3], 0, 0, 0);
        }
        if (node < NN) {
#pragma unroll
            for (int at = 0; at < 4; ++at) {
                float4 r;
                r.x = celu_fast(acc[at][0]);
                r.y = celu_fast(acc[at][1]);
                r.z = celu_fast(acc[at][2]);
                r.w = celu_fast(acc[at][3]);
                *(float4*)&io[(size_t)node * 64 + at * 16 + lhi * 4] = r;
            }
        }
    }
}

// ======================= fallback (atomic path) =======================

__global__ __launch_bounds__(256) void zero_kernel(float4* __restrict__ p, int n4) {
    int i = blockIdx.x * blockDim.x + threadIdx.x;
    if (i < n4) p[i] = make_float4(0.f, 0.f, 0.f, 0.f);
}

__global__ __launch_bounds__(256) void edge_atomic_kernel(
    const float* __restrict__ x, const float* __restrict__ pos,
    const int* __restrict__ ei,
    const float* __restrict__ fw1, const float* __restrict__ fb1,
    const float* __restrict__ fw2, const float* __restrict__ fb2,
    unsigned int* __restrict__ aggr)
{
    __shared__ __align__(16) float s_w1[6 * 64];
    __shared__ __align__(16) float s_b1[64];
    __shared__ __align__(16) float s_w2[64 * 64];
    __shared__ __align__(16) float s_b2[64];

    const int tid = threadIdx.x;
    for (int i = tid; i < 6 * 64; i += 256) s_w1[i] = fw1[i];
    for (int i = tid; i < 64 * 64; i += 256) s_w2[i] = fw2[i];
    if (tid < 64) { s_b1[tid] = fb1[tid]; s_b2[tid] = fb2[tid]; }
    __syncthreads();

    const int e = blockIdx.x * 256 + tid;
    if (e >= NE) return;

    const int s = ei[e];
    const int d = ei[NE + e];

    float in[6];
    in[0] = x[s * 3 + 0];
    in[1] = x[s * 3 + 1];
    in[2] = x[s * 3 + 2];
    in[3] = pos[s * 3 + 0] - pos[d * 3 + 0];
    in[4] = pos[s * 3 + 1] - pos[d * 3 + 1];
    in[5] = pos[s * 3 + 2] - pos[d * 3 + 2];

    float h[64];
#pragma unroll
    for (int k = 0; k < 64; k += 4) {
        float4 acc = *(const float4*)&s_b1[k];
#pragma unroll
        for (int q = 0; q < 6; ++q) {
            float4 w = *(const float4*)&s_w1[q * 64 + k];
            acc.x = fmaf(in[q], w.x, acc.x);
            acc.y = fmaf(in[q], w.y, acc.y);
            acc.z = fmaf(in[q], w.z, acc.z);
            acc.w = fmaf(in[q], w.w, acc.w);
        }
        h[k + 0] = celu_fast(acc.x);
        h[k + 1] = celu_fast(acc.y);
        h[k + 2] = celu_fast(acc.z);
        h[k + 3] = celu_fast(acc.w);
    }

    unsigned int* arow = aggr + (size_t)d * 64;
    for (int o = 0; o < 64; o += 4) {
        float4 acc = *(const float4*)&s_b2[o];
#pragma unroll
        for (int k = 0; k < 64; ++k) {
            float4 w = *(const float4*)&s_w2[k * 64 + o];
            acc.x = fmaf(h[k], w.x, acc.x);
            acc.y = fmaf(h[k], w.y, acc.y);
            acc.z = fmaf(h[k], w.z, acc.z);
            acc.w = fmaf(h[k], w.w, acc.w);
        }
        if (acc.x > 0.f) atomicMax(&arow[o + 0], __float_as_uint(acc.x));
        if (acc.y > 0.f) atomicMax(&arow[o + 1], __float_as_uint(acc.y));
        if (acc.z > 0.f) atomicMax(&arow[o + 2], __float_as_uint(acc.z));
        if (acc.w > 0.f) atomicMax(&arow[o + 3], __float_as_uint(acc.w));
    }
}

__global__ __launch_bounds__(256) void node_valu_kernel(
    const float* __restrict__ x,
    float* io,
    const float* __restrict__ gw1, const float* __restrict__ gb1,
    const float* __restrict__ gw2, const float* __restrict__ gb2)
{
    __shared__ __align__(16) float s_w1[67 * 64];
    __shared__ __align__(16) float s_b1[64];
    __shared__ __align__(16) float s_w2[64 * 64];
    __shared__ __align__(16) float s_b2[64];

    const int tid = threadIdx.x;
    for (int i = tid; i < 67 * 64; i += 256) s_w1[i] = gw1[i];
    for (int i = tid; i < 64 * 64; i += 256) s_w2[i] = gw2[i];
    if (tid < 64) { s_b1[tid] = gb1[tid]; s_b2[tid] = gb2[tid]; }
    __syncthreads();

    const int n = blockIdx.x * 256 + tid;
    if (n >= NN) return;

    float a[64];
#pragma unroll
    for (int k = 0; k < 64; k += 4) {
        float4 v = *(const float4*)&io[(size_t)n * 64 + k];
        a[k + 0] = v.x; a[k + 1] = v.y; a[k + 2] = v.z; a[k + 3] = v.w;
    }
    float xv[3];
    xv[0] = x[n * 3 + 0];
    xv[1] = x[n * 3 + 1];
    xv[2] = x[n * 3 + 2];

    float u[64];
    for (int j = 0; j < 64; j += 4) {
        float4 acc = *(const float4*)&s_b1[j];
#pragma unroll
        for (int k = 0; k < 64; ++k) {
            float4 w = *(const float4*)&s_w1[k * 64 + j];
            acc.x = fmaf(a[k], w.x, acc.x);
            acc.y = fmaf(a[k], w.y, acc.y);
            acc.z = fmaf(a[k], w.z, acc.z);
            acc.w = fmaf(a[k], w.w, acc.w);
        }
#pragma unroll
        for (int q = 0; q < 3; ++q) {
            float4 w = *(const float4*)&s_w1[(64 + q) * 64 + j];
            acc.x = fmaf(xv[q], w.x, acc.x);
            acc.y = fmaf(xv[q], w.y, acc.y);
            acc.z = fmaf(xv[q], w.z, acc.z);
            acc.w = fmaf(xv[q], w.w, acc.w);
        }
        u[j + 0] = celu_fast(acc.x);
        u[j + 1] = celu_fast(acc.y);
        u[j + 2] = celu_fast(acc.z);
        u[j + 3] = celu_fast(acc.w);
    }

    float* orow = &io[(size_t)n * 64];
    for (int j = 0; j < 64; j += 4) {
        float4 acc = *(const float4*)&s_b2[j];
#pragma unroll
        for (int k = 0; k < 64; ++k) {
            float4 w = *(const float4*)&s_w2[k * 64 + j];
            acc.x = fmaf(u[k], w.x, acc.x);
            acc.y = fmaf(u[k], w.y, acc.y);
            acc.z = fmaf(u[k], w.z, acc.z);
            acc.w = fmaf(u[k], w.w, acc.w);
        }
        float4 r;
        r.x = celu_fast(acc.x);
        r.y = celu_fast(acc.y);
        r.z = celu_fast(acc.z);
        r.w = celu_fast(acc.w);
        *(float4*)&orow[j] = r;
    }
}

// ======================= launcher =======================

extern "C" void kernel_launch(void* const* d_in, const int* in_sizes, int n_in,
                              void* d_out, int out_size, void* d_ws, size_t ws_size,
                              hipStream_t stream) {
    const float* x   = (const float*)d_in[0];
    const float* pos = (const float*)d_in[1];
    const int*   ei  = (const int*)d_in[2];
    const float* fw1 = (const float*)d_in[3];
    const float* fb1 = (const float*)d_in[4];
    const float* fw2 = (const float*)d_in[5];
    const float* fb2 = (const float*)d_in[6];
    const float* gw1 = (const float*)d_in[7];
    const float* gb1 = (const float*)d_in[8];
    const float* gw2 = (const float*)d_in[9];
    const float* gb2 = (const float*)d_in[10];
    float* out = (float*)d_out;

    const int n4 = NN * 64 / 4;

    auto al = [](size_t v) { return (v + 255) & ~(size_t)255; };
    const size_t o_gcur = 0;
    const size_t o_w1t  = al(o_gcur + (size_t)NBKT * 4);
    const size_t o_w2t  = al(o_w1t + (size_t)64 * 8 * 2);
    const size_t o_g1t  = al(o_w2t + (size_t)64 * 64 * 2);
    const size_t o_g2t  = al(o_g1t + (size_t)64 * 64 * 2);
    const size_t o_w1x  = al(o_g2t + (size_t)64 * 64 * 2);
    const size_t o_xp   = al(o_w1x + (size_t)192 * 4);
    const size_t o_sd1  = al(o_xp + (size_t)NN * 8 * 4);
    const size_t o_sd2  = al(o_sd1 + (size_t)NBKT * BCAP * 4);
    const size_t need   = o_sd2 + (size_t)NE * 4;

    if (ws_size >= need) {
        char* w = (char*)d_ws;
        u32*    gcur = (u32*)(w + o_gcur);
        __half* w1t  = (__half*)(w + o_w1t);
        __half* w2t  = (__half*)(w + o_w2t);
        __half* g1t  = (__half*)(w + o_g1t);
        __half* g2t  = (__half*)(w + o_g2t);
        float*  w1x  = (float*)(w + o_w1x);
        float*  xp   = (float*)(w + o_xp);
        u32*    sd1  = (u32*)(w + o_sd1);
        u32*    sd2  = (u32*)(w + o_sd2);

        (void)hipMemsetAsync(gcur, 0, (size_t)NBKT * 4, stream);
        binA_prep_kernel<<<197, 512, 0, stream>>>(ei, gcur, sd1, (uint4*)out,
                                                  x, pos, xp,
                                                  fw1, fw2, gw1, gw2,
                                                  w1t, w2t, g1t, g2t, w1x);
        sortB_kernel<<<NBKT, 512, 0, stream>>>(sd1, gcur, sd2);
        edge_fused_kernel<<<NE / 256, 512, 0, stream>>>(xp, sd2, w1t, fb1,
                                                        w2t, fb2, (u32*)out);
        node_mfma_kernel<<<(NN + 127) / 128, 256, 0, stream>>>(xp, out, g1t, w1x,
                                                               gb1, g2t, gb2);
    } else {
        // fallback: atomic path (ws too small)
        zero_kernel<<<(n4 + 255) / 256, 256, 0, stream>>>((float4*)out, n4);
        edge_atomic_kernel<<<NE / 256, 256, 0, stream>>>(x, pos, ei, fw1, fb1,
                                                         fw2, fb2, (unsigned int*)out);
        node_valu_kernel<<<(NN + 255) / 256, 256, 0, stream>>>(x, out, gw1, gb1,
                                                               gw2, gb2);
    }
}

// Round 23
// 141.413 us; speedup vs baseline: 1.0694x; 1.0694x over previous
//
#include <hip/hip_runtime.h>
#include <hip/hip_fp16.h>
#include <math.h>

#define NN 50000
#define NE 1600000
#define NBKT 196         // ceil(50000 / 256)
#define BKT_SHIFT 8      // 256 nodes per bucket
#define BCAP 16384       // fixed bucket capacity (mean 8163, sigma ~90)
#define SCAP 12288       // sortB LDS staging capacity (45 sigma above mean)

typedef unsigned int u32;
typedef unsigned long long u64;
typedef _Float16 f16x8 __attribute__((ext_vector_type(8)));
typedef _Float16 f16x4 __attribute__((ext_vector_type(4)));
typedef float f32x4 __attribute__((ext_vector_type(4)));

// fast celu: __expf is the HW v_exp path; abs err ~1e-7, threshold is 1.97e-2
__device__ __forceinline__ float celu_fast(float v) {
    return v > 0.0f ? v : __expf(v) - 1.0f;
}

// swizzled LDS layout for 128B-row f16 tiles: 8B chunks (4 f16),
// chunk c4 of row r -> half-index r*64 + (c4 ^ ((r&7)<<1))*4
__device__ __forceinline__ __half* hptr(__half* base, int row, int c4) {
    return base + (row << 6) + ((c4 ^ ((row & 7) << 1)) << 2);
}

// ======================= binA + prep fused (512 threads) =======================
__global__ __launch_bounds__(512) void binA_prep_kernel(
    const int* __restrict__ ei, u32* __restrict__ gcur, u32* __restrict__ sd1,
    uint4* __restrict__ aggr4,
    const float* __restrict__ x, const float* __restrict__ pos,
    float* __restrict__ xp,
    const float* __restrict__ fw1, const float* __restrict__ fw2,
    const float* __restrict__ gw1, const float* __restrict__ gw2,
    __half* __restrict__ w1t, __half* __restrict__ w2t,
    __half* __restrict__ g1t, __half* __restrict__ g2t,
    float* __restrict__ w1x)
{
    const int tid = threadIdx.x;
    const int b = blockIdx.x;
    if (b == 196) {
        for (int i = tid; i < 4096; i += 512) {
            const int n = i >> 6, k = i & 63;
            w2t[i] = __float2half(fw2[k * 64 + n]);
            g1t[i] = __float2half(gw1[k * 64 + n]);
            g2t[i] = __float2half(gw2[k * 64 + n]);
        }
        if (tid < 512) {
            const int n = tid >> 3, k = tid & 7;
            w1t[tid] = (k < 6) ? __float2half(fw1[k * 64 + n]) : __half(0.0f);
        }
        if (tid < 192) {
            const int c = tid >> 6, ch = tid & 63;
            w1x[tid] = gw1[(64 + c) * 64 + ch];
        }
        return;
    }

    // prep side-work: zero aggr slice + xp build
    for (int idx = b * 512 + tid; idx < NN * 64 / 4; idx += 196 * 512)
        aggr4[idx] = make_uint4(0u, 0u, 0u, 0u);
    {
        const int n = b * 512 + tid;
        if (n < NN) {
            float4 a, p;
            a.x = x[n * 3 + 0]; a.y = x[n * 3 + 1]; a.z = x[n * 3 + 2]; a.w = 0.f;
            p.x = pos[n * 3 + 0]; p.y = pos[n * 3 + 1]; p.z = pos[n * 3 + 2]; p.w = 0.f;
            *(float4*)&xp[n * 8 + 0] = a;
            *(float4*)&xp[n * 8 + 4] = p;
        }
    }

    // bin 8192 edges via LDS staging
    __shared__ u32 s_hist[NBKT];
    __shared__ u32 s_res[NBKT];
    __shared__ u32 s_lofs[NBKT];
    __shared__ u32 s_cur[NBKT];
    __shared__ u32 s_scan[256];
    __shared__ u32 s_stage[8192];   // 32 KiB

    if (tid < NBKT) { s_hist[tid] = 0u; s_cur[tid] = 0u; }
    __syncthreads();

    const int e0 = b * 8192 + tid * 16;
    const bool valid = (e0 < NE);
    u32 ed[16];
    if (valid) {
        const int4* sp = (const int4*)&ei[e0];
        const int4* dp = (const int4*)&ei[NE + e0];
#pragma unroll
        for (int q = 0; q < 4; ++q) {
            int4 s4 = sp[q];
            int4 d4 = dp[q];
            ed[q * 4 + 0] = ((u32)d4.x << 16) | (u32)s4.x;
            ed[q * 4 + 1] = ((u32)d4.y << 16) | (u32)s4.y;
            ed[q * 4 + 2] = ((u32)d4.z << 16) | (u32)s4.z;
            ed[q * 4 + 3] = ((u32)d4.w << 16) | (u32)s4.w;
        }
#pragma unroll
        for (int q = 0; q < 16; ++q)
            atomicAdd(&s_hist[ed[q] >> 24], 1u);
    }
    __syncthreads();
    if (tid < NBKT && s_hist[tid]) s_res[tid] = atomicAdd(&gcur[tid], s_hist[tid]);
    if (tid < 256) s_scan[tid] = (tid < NBKT) ? s_hist[tid] : 0u;
    __syncthreads();
    for (int d = 1; d < 256; d <<= 1) {
        u32 t = 0u;
        if (tid < 256 && tid >= d) t = s_scan[tid - d];
        __syncthreads();
        if (tid < 256) s_scan[tid] += t;
        __syncthreads();
    }
    if (tid < NBKT) s_lofs[tid] = s_scan[tid] - s_hist[tid];
    __syncthreads();
    if (valid) {
#pragma unroll
        for (int q = 0; q < 16; ++q) {
            const u32 bb = ed[q] >> 24;
            const u32 r = atomicAdd(&s_cur[bb], 1u);
            s_stage[s_lofs[bb] + r] = ed[q];
        }
    }
    __syncthreads();
    const int wv = tid >> 6;
    const int lane = tid & 63;
    for (int bk = wv; bk < NBKT; bk += 8) {
        const u32 cnt = s_hist[bk];
        if (!cnt) continue;
        const u32 lo = s_lofs[bk];
        const u32 gres = s_res[bk];
        for (u32 j = (u32)lane; j < cnt; j += 64) {
            const u32 p = gres + j;
            if (p < BCAP) sd1[(u32)bk * BCAP + p] = s_stage[lo + j];
        }
    }
}

// counting sort within each bucket (256 bins), 512 threads, LDS-staged output
__global__ __launch_bounds__(512) void sortB_kernel(const u32* __restrict__ sd1,
                                                    const u32* __restrict__ gcur,
                                                    u32* __restrict__ sd2) {
    __shared__ u32 s_scan[256];
    __shared__ u32 s_cnt[256];
    __shared__ u32 s_pos[256];
    __shared__ u32 s_stage[SCAP];   // 48 KiB
    const int tid = threadIdx.x;
    const int b = blockIdx.x;

    if (tid < 256) s_scan[tid] = (tid < NBKT) ? gcur[tid] : 0u;
    __syncthreads();
    for (int d = 1; d < 256; d <<= 1) {
        u32 t = 0u;
        if (tid < 256 && tid >= d) t = s_scan[tid - d];
        __syncthreads();
        if (tid < 256) s_scan[tid] += t;
        __syncthreads();
    }
    u32 cnt = gcur[b];
    if (cnt > BCAP) cnt = BCAP;
    const u32 outbase = s_scan[b] - cnt;
    const u32 src = (u32)b * BCAP;

    if (tid < 256) s_cnt[tid] = 0u;
    __syncthreads();
    for (u32 j = tid; j < cnt; j += 512)
        atomicAdd(&s_cnt[(sd1[src + j] >> 16) & 255u], 1u);
    __syncthreads();
    if (tid < 256) s_pos[tid] = s_cnt[tid];
    __syncthreads();
    for (int d = 1; d < 256; d <<= 1) {
        u32 t = 0u;
        if (tid < 256 && tid >= d) t = s_pos[tid - d];
        __syncthreads();
        if (tid < 256) s_pos[tid] += t;
        __syncthreads();
    }
    if (tid < 256) s_pos[tid] -= s_cnt[tid];
    __syncthreads();

    if (cnt <= SCAP) {
        for (u32 j = tid; j < cnt; j += 512) {
            const u32 sd = sd1[src + j];
            const u32 dl = (sd >> 16) & 255u;
            const u32 r = atomicAdd(&s_pos[dl], 1u);
            s_stage[r] = sd;
        }
        __syncthreads();
        for (u32 j = tid; j < cnt; j += 512)
            sd2[outbase + j] = s_stage[j];
    } else {
        for (u32 j = tid; j < cnt; j += 512) {
            const u32 sd = sd1[src + j];
            const u32 dl = (sd >> 16) & 255u;
            const u32 r = atomicAdd(&s_pos[dl], 1u);
            sd2[outbase + r] = sd;
        }
    }
}

// ======================= fused edge+gather kernel: 512 threads, register-lean =======================
// 8 waves per block; each wave owns 32 edge rows. L2 phase processes output tiles
// in 2 passes of 2 with A-fragments loaded from L2-cached w2t inside the loop:
// peak live set ~50 regs -> fits the 64-reg budget of 8 waves/SIMD with no spill.
__global__ __launch_bounds__(512, 8) void edge_fused_kernel(
    const float* __restrict__ xp,
    const u32* __restrict__ sdb,
    const __half* __restrict__ w1t, const float* __restrict__ fb1,
    const __half* __restrict__ w2t, const float* __restrict__ fb2,
    u32* __restrict__ aggr)
{
    __shared__ __align__(16) __half s_in[256 * 8];   // 4 KiB
    __shared__ __align__(16) __half s_h[256 * 64];   // 32 KiB, swizzled
    __shared__ u32 s_d[256];
    __shared__ u32 s_start[257];
    __shared__ u32 s_nseg;

    const int tid = threadIdx.x;
    // bijective XCD-chunked swizzle (nwg=6250: q=781, r=2)
    const int xcd = blockIdx.x & 7;
    const int idx = blockIdx.x >> 3;
    const int ebid = (xcd < 2) ? xcd * 782 + idx : 2 * 782 + (xcd - 2) * 781 + idx;

    // staging: first 256 threads handle one edge each
    if (tid < 256) {
        const int i = ebid * 256 + tid;
        const u32 w = sdb[i];
        const int s = (int)(w & 0xFFFFu);
        const int d = (int)(w >> 16);
        s_d[tid] = (u32)d;
        const float4* xp4 = (const float4*)xp;
        float4 axs = xp4[s * 2];
        float4 aps = xp4[s * 2 + 1];
        float4 apd = xp4[d * 2 + 1];
        union { uint4 u; __half2 h2[4]; } pk;
        pk.h2[0] = __floats2half2_rn(axs.x, axs.y);
        pk.h2[1] = __floats2half2_rn(axs.z, aps.x - apd.x);
        pk.h2[2] = __floats2half2_rn(aps.y - apd.y, aps.z - apd.z);
        pk.h2[3] = __floats2half2_rn(0.f, 0.f);
        *(uint4*)&s_in[tid * 8] = pk.u;
    }
    __syncthreads();   // s_in + s_d ready

    const int l = tid & 63;
    const int wv = tid >> 6;       // 0..7
    const int rbase = wv << 5;     // wave's 32-edge base row
    const int lrow = l & 15;
    const int lhi = l >> 4;

    // ---- layer 1 on MFMA (2 row-groups per wave) ----
    const f16x8 zero8 = {};
    f16x8 b1f[2];
#pragma unroll
    for (int nt = 0; nt < 2; ++nt) {
        b1f[nt] = zero8;
        if (lhi == 0)
            b1f[nt] = *(const f16x8*)&s_in[(rbase + nt * 16 + lrow) * 8];
    }

#pragma unroll
    for (int mt = 0; mt < 4; ++mt) {
        f16x8 a = zero8;
        if (lhi == 0) a = *(const f16x8*)&w1t[(mt * 16 + lrow) * 8];
        const f32x4 c0 = *(const f32x4*)&fb1[mt * 16 + lhi * 4];
#pragma unroll
        for (int nt = 0; nt < 2; ++nt) {
            f32x4 z = __builtin_amdgcn_mfma_f32_16x16x32_f16(a, b1f[nt], c0, 0, 0, 0);
            const int row = rbase + nt * 16 + lrow;
            union { uint2 u; __half2 h2[2]; } pk;
            pk.h2[0] = __floats2half2_rn(celu_fast(z[0]), celu_fast(z[1]));
            pk.h2[1] = __floats2half2_rn(celu_fast(z[2]), celu_fast(z[3]));
            *(uint2*)hptr(s_h, row, mt * 4 + lhi) = pk.u;
        }
    }

    // wave 0: segment head-scan over sorted dst -> s_start[0..nseg]
    if (tid < 64) {
        u32 base = 0;
        for (int c = 0; c < 4; ++c) {
            const int t = c * 64 + tid;
            const bool head = (t == 0) || (s_d[t] != s_d[t - 1]);
            const u64 m = __ballot(head);
            const u32 pos0 = base + (u32)__popcll(m & ((1ull << tid) - 1ull));
            if (head) s_start[pos0] = (u32)t;
            base += (u32)__popcll(m);
        }
        if (tid == 0) { s_nseg = base; s_start[base] = 256u; }
    }

    __syncthreads();   // s_h (h values) ready

    // ---- layer 2 on MFMA, register-lean, in-place writeback ----
#pragma unroll
    for (int g = 0; g < 2; ++g) {
        const int rb = rbase + g * 16 + lrow;
        // read both B fragments into registers before any writeback of this row
        f16x8 b0 = *(const f16x8*)hptr(s_h, rb, (0 * 4 + lhi) * 2);
        f16x8 b1 = *(const f16x8*)hptr(s_h, rb, (1 * 4 + lhi) * 2);
#pragma unroll
        for (int half = 0; half < 2; ++half) {
            f32x4 acc[2];
#pragma unroll
            for (int t2 = 0; t2 < 2; ++t2)
                acc[t2] = *(const f32x4*)(fb2 + (half * 2 + t2) * 16 + (lhi << 2));
#pragma unroll
            for (int kt = 0; kt < 2; ++kt) {
                const f16x8 b = kt ? b1 : b0;
#pragma unroll
                for (int t2 = 0; t2 < 2; ++t2) {
                    const int at = half * 2 + t2;
                    f16x8 a = *(const f16x8*)(w2t + ((at * 16 + lrow) << 6) + kt * 32 + (lhi << 3));
                    acc[t2] = __builtin_amdgcn_mfma_f32_16x16x32_f16(a, b, acc[t2], 0, 0, 0);
                }
            }
#pragma unroll
            for (int t2 = 0; t2 < 2; ++t2) {
                const int at = half * 2 + t2;
                union { uint2 u; __half2 h2[2]; } pk;
                pk.h2[0] = __floats2half2_rn(acc[t2][0], acc[t2][1]);
                pk.h2[1] = __floats2half2_rn(acc[t2][2], acc[t2][3]);
                *(uint2*)hptr(s_h, rb, at * 4 + lhi) = pk.u;
            }
        }
    }
    __syncthreads();   // messages + segment table ready

    // ---- segmented max-reduce: 16 half-waves, 2 rows/iter ----
    const int hw = tid >> 5;       // 0..15
    const int lane2 = tid & 31;
    const int sub = lane2 >> 4;
    const int c8 = lane2 & 15;
    const u32 nseg = s_nseg;
    for (u32 j = (u32)hw; j < nseg; j += 16) {
        const u32 lo = s_start[j];
        const u32 hi = s_start[j + 1];
        const u32 node = s_d[lo];
        f16x4 m = {};
        for (u32 r0 = lo; r0 < hi; r0 += 2) {
            const u32 r = r0 + (u32)sub;
            if (r < hi) {
                f16x4 v = *(const f16x4*)hptr(s_h, (int)r, c8);
                m = __builtin_elementwise_max(m, v);
            }
        }
        union { f16x4 v; int w2[2]; } a, b;
        a.v = m;
        b.w2[0] = __shfl_down(a.w2[0], 16, 32);
        b.w2[1] = __shfl_down(a.w2[1], 16, 32);
        f16x4 mm = __builtin_elementwise_max(a.v, b.v);
        if (sub == 0) {
            if (lo > 0u && hi < 256u) {
                float4 st;
                st.x = fmaxf((float)mm[0], 0.f);
                st.y = fmaxf((float)mm[1], 0.f);
                st.z = fmaxf((float)mm[2], 0.f);
                st.w = fmaxf((float)mm[3], 0.f);
                *(float4*)((float*)aggr + (size_t)node * 64 + c8 * 4) = st;
            } else {
                u32* arow = aggr + (size_t)node * 64 + c8 * 4;
#pragma unroll
                for (int t = 0; t < 4; ++t) {
                    float f = (float)mm[t];
                    if (f > 0.f) atomicMax(&arow[t], __float_as_uint(f));
                }
            }
        }
    }
}

// ======================= node update MLP on MFMA: 256 threads, 128 nodes =======================
__global__ __launch_bounds__(256) void node_mfma_kernel(
    const float* __restrict__ xp,
    float* io,   // d_out: aggr in, final out
    const __half* __restrict__ g1t, const float* __restrict__ w1x,
    const float* __restrict__ gb1,
    const __half* __restrict__ g2t, const float* __restrict__ gb2)
{
    __shared__ __align__(16) __half s_a[128 * 64];
    __shared__ __align__(16) __half s_u[128 * 64];
    __shared__ __align__(16) float s_x[128 * 4];

    const int tid = threadIdx.x;
    const int n0 = blockIdx.x * 128;

#pragma unroll
    for (int it = 0; it < 8; ++it) {
        const int idx = it * 256 + tid;
        const int row = idx >> 4, c8 = idx & 15;
        const int g = n0 + row;
        float4 v = make_float4(0.f, 0.f, 0.f, 0.f);
        if (g < NN) v = *(const float4*)&io[(size_t)g * 64 + c8 * 4];
        union { uint2 u; __half2 h2[2]; } pk;
        pk.h2[0] = __floats2half2_rn(v.x, v.y);
        pk.h2[1] = __floats2half2_rn(v.z, v.w);
        *(uint2*)hptr(s_a, row, c8) = pk.u;
    }
    if (tid < 128) {
        const int g = n0 + tid;
        float4 a = make_float4(0.f, 0.f, 0.f, 0.f);
        if (g < NN) a = *(const float4*)&xp[(size_t)g * 8];
        *(float4*)&s_x[tid * 4] = a;
    }
    __syncthreads();

    const int l = tid & 63;
    const int wv = tid >> 6;           // 0..3, each wave owns 32 rows
    const int lrow = l & 15;
    const int lhi = l >> 4;

    f16x8 a1[4][2], a2[4][2];
    f32x4 bias1[4], bias2[4];
    f32x4 wx0[4], wx1[4], wx2[4];
#pragma unroll
    for (int at = 0; at < 4; ++at) {
#pragma unroll
        for (int kt = 0; kt < 2; ++kt) {
            const int off = ((at * 16 + lrow) << 6) + kt * 32 + (lhi << 3);
            a1[at][kt] = *(const f16x8*)(g1t + off);
            a2[at][kt] = *(const f16x8*)(g2t + off);
        }
        bias1[at] = *(const f32x4*)&gb1[at * 16 + lhi * 4];
        bias2[at] = *(const f32x4*)&gb2[at * 16 + lhi * 4];
        const int ch = at * 16 + lhi * 4;
        wx0[at] = *(const f32x4*)&w1x[0 * 64 + ch];
        wx1[at] = *(const f32x4*)&w1x[1 * 64 + ch];
        wx2[at] = *(const f32x4*)&w1x[2 * 64 + ch];
    }

#pragma unroll
    for (int g = 0; g < 2; ++g) {
        const int rb = wv * 32 + g * 16 + lrow;
        f32x4 acc[4];
#pragma unroll
        for (int at = 0; at < 4; ++at) acc[at] = bias1[at];
#pragma unroll
        for (int kt = 0; kt < 2; ++kt) {
            f16x8 b = *(const f16x8*)hptr(s_a, rb, (kt * 4 + lhi) * 2);
            acc[0] = __builtin_amdgcn_mfma_f32_16x16x32_f16(a1[0][kt], b, acc[0], 0, 0, 0);
            acc[1] = __builtin_amdgcn_mfma_f32_16x16x32_f16(a1[1][kt], b, acc[1], 0, 0, 0);
            acc[2] = __builtin_amdgcn_mfma_f32_16x16x32_f16(a1[2][kt], b, acc[2], 0, 0, 0);
            acc[3] = __builtin_amdgcn_mfma_f32_16x16x32_f16(a1[3][kt], b, acc[3], 0, 0, 0);
        }
        const float x0 = s_x[rb * 4 + 0];
        const float x1 = s_x[rb * 4 + 1];
        const float x2 = s_x[rb * 4 + 2];
#pragma unroll
        for (int at = 0; at < 4; ++at) {
            f32x4 z = acc[at];
#pragma unroll
            for (int t = 0; t < 4; ++t)
                z[t] = fmaf(x0, wx0[at][t], fmaf(x1, wx1[at][t], fmaf(x2, wx2[at][t], z[t])));
            union { uint2 u; __half2 h2[2]; } pk;
            pk.h2[0] = __floats2half2_rn(celu_fast(z[0]), celu_fast(z[1]));
            pk.h2[1] = __floats2half2_rn(celu_fast(z[2]), celu_fast(z[3]));
            *(uint2*)hptr(s_u, rb, at * 4 + lhi) = pk.u;
        }
    }
    __syncthreads();

#pragma unroll
    for (int g = 0; g < 2; ++g) {
        const int rb = wv * 32 + g * 16 + lrow;
        const int node = n0 + rb;
        f32x4 acc[4];
#pragma unroll
        for (int at = 0; at < 4; ++at) acc[at] = bias2[at];
#pragma unroll
        for (int kt = 0; kt < 2; ++kt) {
            f16x8 b = *(const f16x8*)hptr(s_u, rb, (kt * 4 + lhi) * 2);
            acc[0] = __builtin_amdgcn_mfma_f32_16x16x32_f16(a2[0][kt], b, acc[0], 0, 0, 0);
            acc[1] = __builtin_amdgcn_mfma_f32_16x16x32_f16(a2[1][kt], b, acc[1], 0, 0, 0);
            acc[2] = __builtin_amdgcn_mfma_f32_16x16x32_f16(a2[2][kt], b, acc[2], 0, 0, 0);
            acc[3] = __builtin_amdgcn_mfma_f32_16x16x32_f16(a2[3][kt], b, acc[3], 0, 0, 0);
        }
        if (node < NN) {
#pragma unroll
            for (int at = 0; at < 4; ++at) {
                float4 r;
                r.x = celu_fast(acc[at][0]);
                r.y = celu_fast(acc[at][1]);
                r.z = celu_fast(acc[at][2]);
                r.w = celu_fast(acc[at][3]);
                *(float4*)&io[(size_t)node * 64 + at * 16 + lhi * 4] = r;
            }
        }
    }
}

// ======================= fallback (atomic path) =======================

__global__ __launch_bounds__(256) void zero_kernel(float4* __restrict__ p, int n4) {
    int i = blockIdx.x * blockDim.x + threadIdx.x;
    if (i < n4) p[i] = make_float4(0.f, 0.f, 0.f, 0.f);
}

__global__ __launch_bounds__(256) void edge_atomic_kernel(
    const float* __restrict__ x, const float* __restrict__ pos,
    const int* __restrict__ ei,
    const float* __restrict__ fw1, const float* __restrict__ fb1,
    const float* __restrict__ fw2, const float* __restrict__ fb2,
    unsigned int* __restrict__ aggr)
{
    __shared__ __align__(16) float s_w1[6 * 64];
    __shared__ __align__(16) float s_b1[64];
    __shared__ __align__(16) float s_w2[64 * 64];
    __shared__ __align__(16) float s_b2[64];

    const int tid = threadIdx.x;
    for (int i = tid; i < 6 * 64; i += 256) s_w1[i] = fw1[i];
    for (int i = tid; i < 64 * 64; i += 256) s_w2[i] = fw2[i];
    if (tid < 64) { s_b1[tid] = fb1[tid]; s_b2[tid] = fb2[tid]; }
    __syncthreads();

    const int e = blockIdx.x * 256 + tid;
    if (e >= NE) return;

    const int s = ei[e];
    const int d = ei[NE + e];

    float in[6];
    in[0] = x[s * 3 + 0];
    in[1] = x[s * 3 + 1];
    in[2] = x[s * 3 + 2];
    in[3] = pos[s * 3 + 0] - pos[d * 3 + 0];
    in[4] = pos[s * 3 + 1] - pos[d * 3 + 1];
    in[5] = pos[s * 3 + 2] - pos[d * 3 + 2];

    float h[64];
#pragma unroll
    for (int k = 0; k < 64; k += 4) {
        float4 acc = *(const float4*)&s_b1[k];
#pragma unroll
        for (int q = 0; q < 6; ++q) {
            float4 w = *(const float4*)&s_w1[q * 64 + k];
            acc.x = fmaf(in[q], w.x, acc.x);
            acc.y = fmaf(in[q], w.y, acc.y);
            acc.z = fmaf(in[q], w.z, acc.z);
            acc.w = fmaf(in[q], w.w, acc.w);
        }
        h[k + 0] = celu_fast(acc.x);
        h[k + 1] = celu_fast(acc.y);
        h[k + 2] = celu_fast(acc.z);
        h[k + 3] = celu_fast(acc.w);
    }

    unsigned int* arow = aggr + (size_t)d * 64;
    for (int o = 0; o < 64; o += 4) {
        float4 acc = *(const float4*)&s_b2[o];
#pragma unroll
        for (int k = 0; k < 64; ++k) {
            float4 w = *(const float4*)&s_w2[k * 64 + o];
            acc.x = fmaf(h[k], w.x, acc.x);
            acc.y = fmaf(h[k], w.y, acc.y);
            acc.z = fmaf(h[k], w.z, acc.z);
            acc.w = fmaf(h[k], w.w, acc.w);
        }
        if (acc.x > 0.f) atomicMax(&arow[o + 0], __float_as_uint(acc.x));
        if (acc.y > 0.f) atomicMax(&arow[o + 1], __float_as_uint(acc.y));
        if (acc.z > 0.f) atomicMax(&arow[o + 2], __float_as_uint(acc.z));
        if (acc.w > 0.f) atomicMax(&arow[o + 3], __float_as_uint(acc.w));
    }
}

__global__ __launch_bounds__(256) void node_valu_kernel(
    const float* __restrict__ x,
    float* io,
    const float* __restrict__ gw1, const float* __restrict__ gb1,
    const float* __restrict__ gw2, const float* __restrict__ gb2)
{
    __shared__ __align__(16) float s_w1[67 * 64];
    __shared__ __align__(16) float s_b1[64];
    __shared__ __align__(16) float s_w2[64 * 64];
    __shared__ __align__(16) float s_b2[64];

    const int tid = threadIdx.x;
    for (int i = tid; i < 67 * 64; i += 256) s_w1[i] = gw1[i];
    for (int i = tid; i < 64 * 64; i += 256) s_w2[i] = gw2[i];
    if (tid < 64) { s_b1[tid] = gb1[tid]; s_b2[tid] = gb2[tid]; }
    __syncthreads();

    const int n = blockIdx.x * 256 + tid;
    if (n >= NN) return;

    float a[64];
#pragma unroll
    for (int k = 0; k < 64; k += 4) {
        float4 v = *(const float4*)&io[(size_t)n * 64 + k];
        a[k + 0] = v.x; a[k + 1] = v.y; a[k + 2] = v.z; a[k + 3] = v.w;
    }
    float xv[3];
    xv[0] = x[n * 3 + 0];
    xv[1] = x[n * 3 + 1];
    xv[2] = x[n * 3 + 2];

    float u[64];
    for (int j = 0; j < 64; j += 4) {
        float4 acc = *(const float4*)&s_b1[j];
#pragma unroll
        for (int k = 0; k < 64; ++k) {
            float4 w = *(const float4*)&s_w1[k * 64 + j];
            acc.x = fmaf(a[k], w.x, acc.x);
            acc.y = fmaf(a[k], w.y, acc.y);
            acc.z = fmaf(a[k], w.z, acc.z);
            acc.w = fmaf(a[k], w.w, acc.w);
        }
#pragma unroll
        for (int q = 0; q < 3; ++q) {
            float4 w = *(const float4*)&s_w1[(64 + q) * 64 + j];
            acc.x = fmaf(xv[q], w.x, acc.x);
            acc.y = fmaf(xv[q], w.y, acc.y);
            acc.z = fmaf(xv[q], w.z, acc.z);
            acc.w = fmaf(xv[q], w.w, acc.w);
        }
        u[j + 0] = celu_fast(acc.x);
        u[j + 1] = celu_fast(acc.y);
        u[j + 2] = celu_fast(acc.z);
        u[j + 3] = celu_fast(acc.w);
    }

    float* orow = &io[(size_t)n * 64];
    for (int j = 0; j < 64; j += 4) {
        float4 acc = *(const float4*)&s_b2[j];
#pragma unroll
        for (int k = 0; k < 64; ++k) {
            float4 w = *(const float4*)&s_w2[k * 64 + j];
            acc.x = fmaf(u[k], w.x, acc.x);
            acc.y = fmaf(u[k], w.y, acc.y);
            acc.z = fmaf(u[k], w.z, acc.z);
            acc.w = fmaf(u[k], w.w, acc.w);
        }
        float4 r;
        r.x = celu_fast(acc.x);
        r.y = celu_fast(acc.y);
        r.z = celu_fast(acc.z);
        r.w = celu_fast(acc.w);
        *(float4*)&orow[j] = r;
    }
}

// ======================= launcher =======================

extern "C" void kernel_launch(void* const* d_in, const int* in_sizes, int n_in,
                              void* d_out, int out_size, void* d_ws, size_t ws_size,
                              hipStream_t stream) {
    const float* x   = (const float*)d_in[0];
    const float* pos = (const float*)d_in[1];
    const int*   ei  = (const int*)d_in[2];
    const float* fw1 = (const float*)d_in[3];
    const float* fb1 = (const float*)d_in[4];
    const float* fw2 = (const float*)d_in[5];
    const float* fb2 = (const float*)d_in[6];
    const float* gw1 = (const float*)d_in[7];
    const float* gb1 = (const float*)d_in[8];
    const float* gw2 = (const float*)d_in[9];
    const float* gb2 = (const float*)d_in[10];
    float* out = (float*)d_out;

    const int n4 = NN * 64 / 4;

    auto al = [](size_t v) { return (v + 255) & ~(size_t)255; };
    const size_t o_gcur = 0;
    const size_t o_w1t  = al(o_gcur + (size_t)NBKT * 4);
    const size_t o_w2t  = al(o_w1t + (size_t)64 * 8 * 2);
    const size_t o_g1t  = al(o_w2t + (size_t)64 * 64 * 2);
    const size_t o_g2t  = al(o_g1t + (size_t)64 * 64 * 2);
    const size_t o_w1x  = al(o_g2t + (size_t)64 * 64 * 2);
    const size_t o_xp   = al(o_w1x + (size_t)192 * 4);
    const size_t o_sd1  = al(o_xp + (size_t)NN * 8 * 4);
    const size_t o_sd2  = al(o_sd1 + (size_t)NBKT * BCAP * 4);
    const size_t need   = o_sd2 + (size_t)NE * 4;

    if (ws_size >= need) {
        char* w = (char*)d_ws;
        u32*    gcur = (u32*)(w + o_gcur);
        __half* w1t  = (__half*)(w + o_w1t);
        __half* w2t  = (__half*)(w + o_w2t);
        __half* g1t  = (__half*)(w + o_g1t);
        __half* g2t  = (__half*)(w + o_g2t);
        float*  w1x  = (float*)(w + o_w1x);
        float*  xp   = (float*)(w + o_xp);
        u32*    sd1  = (u32*)(w + o_sd1);
        u32*    sd2  = (u32*)(w + o_sd2);

        (void)hipMemsetAsync(gcur, 0, (size_t)NBKT * 4, stream);
        binA_prep_kernel<<<197, 512, 0, stream>>>(ei, gcur, sd1, (uint4*)out,
                                                  x, pos, xp,
                                                  fw1, fw2, gw1, gw2,
                                                  w1t, w2t, g1t, g2t, w1x);
        sortB_kernel<<<NBKT, 512, 0, stream>>>(sd1, gcur, sd2);
        edge_fused_kernel<<<NE / 256, 512, 0, stream>>>(xp, sd2, w1t, fb1,
                                                        w2t, fb2, (u32*)out);
        node_mfma_kernel<<<(NN + 127) / 128, 256, 0, stream>>>(xp, out, g1t, w1x,
                                                               gb1, g2t, gb2);
    } else {
        // fallback: atomic path (ws too small)
        zero_kernel<<<(n4 + 255) / 256, 256, 0, stream>>>((float4*)out, n4);
        edge_atomic_kernel<<<NE / 256, 256, 0, stream>>>(x, pos, ei, fw1, fb1,
                                                         fw2, fb2, (unsigned int*)out);
        node_valu_kernel<<<(NN + 255) / 256, 256, 0, stream>>>(x, out, gw1, gb1,
                                                               gw2, gb2);
    }
}

// Round 24
// 115.877 us; speedup vs baseline: 1.3051x; 1.2204x over previous
//
#include <hip/hip_runtime.h>
#include <hip/hip_fp16.h>
#include <math.h>

#define NN 50000
#define NE 1600000
#define NBKT 196         // ceil(50000 / 256)
#define BKT_SHIFT 8      // 256 nodes per bucket
#define BCAP 16384       // fixed bucket capacity (mean 8163, sigma ~90)
#define SCAP 12288       // sortB LDS staging capacity (45 sigma above mean)

typedef unsigned int u32;
typedef unsigned long long u64;
typedef _Float16 f16x8 __attribute__((ext_vector_type(8)));
typedef _Float16 f16x4 __attribute__((ext_vector_type(4)));
typedef float f32x4 __attribute__((ext_vector_type(4)));

// fast celu: __expf is the HW v_exp path; abs err ~1e-7, threshold is 1.97e-2
__device__ __forceinline__ float celu_fast(float v) {
    return v > 0.0f ? v : __expf(v) - 1.0f;
}

// swizzled LDS layout for 128B-row f16 tiles: 8B chunks (4 f16),
// chunk c4 of row r -> half-index r*64 + (c4 ^ ((r&7)<<1))*4
__device__ __forceinline__ __half* hptr(__half* base, int row, int c4) {
    return base + (row << 6) + ((c4 ^ ((row & 7) << 1)) << 2);
}

// ======================= binA + prep fused (512 threads) =======================
__global__ __launch_bounds__(512) void binA_prep_kernel(
    const int* __restrict__ ei, u32* __restrict__ gcur, u32* __restrict__ sd1,
    uint4* __restrict__ aggr4,
    const float* __restrict__ x, const float* __restrict__ pos,
    float* __restrict__ xp,
    const float* __restrict__ fw1, const float* __restrict__ fw2,
    const float* __restrict__ gw1, const float* __restrict__ gw2,
    __half* __restrict__ w1t, __half* __restrict__ w2t,
    __half* __restrict__ g1t, __half* __restrict__ g2t,
    float* __restrict__ w1x)
{
    const int tid = threadIdx.x;
    const int b = blockIdx.x;
    if (b == 196) {
        for (int i = tid; i < 4096; i += 512) {
            const int n = i >> 6, k = i & 63;
            w2t[i] = __float2half(fw2[k * 64 + n]);
            g1t[i] = __float2half(gw1[k * 64 + n]);
            g2t[i] = __float2half(gw2[k * 64 + n]);
        }
        if (tid < 512) {
            const int n = tid >> 3, k = tid & 7;
            w1t[tid] = (k < 6) ? __float2half(fw1[k * 64 + n]) : __half(0.0f);
        }
        if (tid < 192) {
            const int c = tid >> 6, ch = tid & 63;
            w1x[tid] = gw1[(64 + c) * 64 + ch];
        }
        return;
    }

    // prep side-work: zero aggr slice + xp build
    for (int idx = b * 512 + tid; idx < NN * 64 / 4; idx += 196 * 512)
        aggr4[idx] = make_uint4(0u, 0u, 0u, 0u);
    {
        const int n = b * 512 + tid;
        if (n < NN) {
            float4 a, p;
            a.x = x[n * 3 + 0]; a.y = x[n * 3 + 1]; a.z = x[n * 3 + 2]; a.w = 0.f;
            p.x = pos[n * 3 + 0]; p.y = pos[n * 3 + 1]; p.z = pos[n * 3 + 2]; p.w = 0.f;
            *(float4*)&xp[n * 8 + 0] = a;
            *(float4*)&xp[n * 8 + 4] = p;
        }
    }

    // bin 8192 edges via LDS staging
    __shared__ u32 s_hist[NBKT];
    __shared__ u32 s_res[NBKT];
    __shared__ u32 s_lofs[NBKT];
    __shared__ u32 s_cur[NBKT];
    __shared__ u32 s_scan[256];
    __shared__ u32 s_stage[8192];   // 32 KiB

    if (tid < NBKT) { s_hist[tid] = 0u; s_cur[tid] = 0u; }
    __syncthreads();

    const int e0 = b * 8192 + tid * 16;
    const bool valid = (e0 < NE);
    u32 ed[16];
    if (valid) {
        const int4* sp = (const int4*)&ei[e0];
        const int4* dp = (const int4*)&ei[NE + e0];
#pragma unroll
        for (int q = 0; q < 4; ++q) {
            int4 s4 = sp[q];
            int4 d4 = dp[q];
            ed[q * 4 + 0] = ((u32)d4.x << 16) | (u32)s4.x;
            ed[q * 4 + 1] = ((u32)d4.y << 16) | (u32)s4.y;
            ed[q * 4 + 2] = ((u32)d4.z << 16) | (u32)s4.z;
            ed[q * 4 + 3] = ((u32)d4.w << 16) | (u32)s4.w;
        }
#pragma unroll
        for (int q = 0; q < 16; ++q)
            atomicAdd(&s_hist[ed[q] >> 24], 1u);
    }
    __syncthreads();
    if (tid < NBKT && s_hist[tid]) s_res[tid] = atomicAdd(&gcur[tid], s_hist[tid]);
    if (tid < 256) s_scan[tid] = (tid < NBKT) ? s_hist[tid] : 0u;
    __syncthreads();
    for (int d = 1; d < 256; d <<= 1) {
        u32 t = 0u;
        if (tid < 256 && tid >= d) t = s_scan[tid - d];
        __syncthreads();
        if (tid < 256) s_scan[tid] += t;
        __syncthreads();
    }
    if (tid < NBKT) s_lofs[tid] = s_scan[tid] - s_hist[tid];
    __syncthreads();
    if (valid) {
#pragma unroll
        for (int q = 0; q < 16; ++q) {
            const u32 bb = ed[q] >> 24;
            const u32 r = atomicAdd(&s_cur[bb], 1u);
            s_stage[s_lofs[bb] + r] = ed[q];
        }
    }
    __syncthreads();
    const int wv = tid >> 6;
    const int lane = tid & 63;
    for (int bk = wv; bk < NBKT; bk += 8) {
        const u32 cnt = s_hist[bk];
        if (!cnt) continue;
        const u32 lo = s_lofs[bk];
        const u32 gres = s_res[bk];
        for (u32 j = (u32)lane; j < cnt; j += 64) {
            const u32 p = gres + j;
            if (p < BCAP) sd1[(u32)bk * BCAP + p] = s_stage[lo + j];
        }
    }
}

// counting sort within each bucket (256 bins), 512 threads, LDS-staged output
__global__ __launch_bounds__(512) void sortB_kernel(const u32* __restrict__ sd1,
                                                    const u32* __restrict__ gcur,
                                                    u32* __restrict__ sd2) {
    __shared__ u32 s_scan[256];
    __shared__ u32 s_cnt[256];
    __shared__ u32 s_pos[256];
    __shared__ u32 s_stage[SCAP];   // 48 KiB
    const int tid = threadIdx.x;
    const int b = blockIdx.x;

    if (tid < 256) s_scan[tid] = (tid < NBKT) ? gcur[tid] : 0u;
    __syncthreads();
    for (int d = 1; d < 256; d <<= 1) {
        u32 t = 0u;
        if (tid < 256 && tid >= d) t = s_scan[tid - d];
        __syncthreads();
        if (tid < 256) s_scan[tid] += t;
        __syncthreads();
    }
    u32 cnt = gcur[b];
    if (cnt > BCAP) cnt = BCAP;
    const u32 outbase = s_scan[b] - cnt;
    const u32 src = (u32)b * BCAP;

    if (tid < 256) s_cnt[tid] = 0u;
    __syncthreads();
    for (u32 j = tid; j < cnt; j += 512)
        atomicAdd(&s_cnt[(sd1[src + j] >> 16) & 255u], 1u);
    __syncthreads();
    if (tid < 256) s_pos[tid] = s_cnt[tid];
    __syncthreads();
    for (int d = 1; d < 256; d <<= 1) {
        u32 t = 0u;
        if (tid < 256 && tid >= d) t = s_pos[tid - d];
        __syncthreads();
        if (tid < 256) s_pos[tid] += t;
        __syncthreads();
    }
    if (tid < 256) s_pos[tid] -= s_cnt[tid];
    __syncthreads();

    if (cnt <= SCAP) {
        for (u32 j = tid; j < cnt; j += 512) {
            const u32 sd = sd1[src + j];
            const u32 dl = (sd >> 16) & 255u;
            const u32 r = atomicAdd(&s_pos[dl], 1u);
            s_stage[r] = sd;
        }
        __syncthreads();
        for (u32 j = tid; j < cnt; j += 512)
            sd2[outbase + j] = s_stage[j];
    } else {
        for (u32 j = tid; j < cnt; j += 512) {
            const u32 sd = sd1[src + j];
            const u32 dl = (sd >> 16) & 255u;
            const u32 r = atomicAdd(&s_pos[dl], 1u);
            sd2[outbase + r] = sd;
        }
    }
}

// ======================= fused edge+gather kernel (best-known R19/R20: 256 thr, 4 waves) =======================
__global__ __launch_bounds__(256, 4) void edge_fused_kernel(
    const float* __restrict__ xp,
    const u32* __restrict__ sdb,
    const __half* __restrict__ w1t, const float* __restrict__ fb1,
    const __half* __restrict__ w2t, const float* __restrict__ fb2,
    u32* __restrict__ aggr)
{
    __shared__ __align__(16) __half s_in[256 * 8];   // 4 KiB
    __shared__ __align__(16) __half s_h[256 * 64];   // 32 KiB, swizzled
    __shared__ u32 s_d[256];
    __shared__ u32 s_start[257];
    __shared__ u32 s_nseg;

    const int tid = threadIdx.x;
    // bijective XCD-chunked swizzle (nwg=6250: q=781, r=2)
    const int xcd = blockIdx.x & 7;
    const int idx = blockIdx.x >> 3;
    const int ebid = (xcd < 2) ? xcd * 782 + idx : 2 * 782 + (xcd - 2) * 781 + idx;

    const int i = ebid * 256 + tid;   // NE % 256 == 0
    const u32 w = sdb[i];
    const int s = (int)(w & 0xFFFFu);
    const int d = (int)(w >> 16);
    s_d[tid] = (u32)d;

    {
        const float4* xp4 = (const float4*)xp;
        float4 axs = xp4[s * 2];       // x0,x1,x2,0
        float4 aps = xp4[s * 2 + 1];   // p0,p1,p2,0
        float4 apd = xp4[d * 2 + 1];
        union { uint4 u; __half2 h2[4]; } pk;
        pk.h2[0] = __floats2half2_rn(axs.x, axs.y);
        pk.h2[1] = __floats2half2_rn(axs.z, aps.x - apd.x);
        pk.h2[2] = __floats2half2_rn(aps.y - apd.y, aps.z - apd.z);
        pk.h2[3] = __floats2half2_rn(0.f, 0.f);
        *(uint4*)&s_in[tid * 8] = pk.u;
    }
    __syncthreads();   // s_in + s_d ready

    const int l = tid & 63;
    const int wbase = tid & 192;   // wave's 64-edge base row
    const int lrow = l & 15;
    const int lhi = l >> 4;

    // ---- layer 1 on MFMA ----
    const f16x8 zero8 = {};
    f16x8 b1f[4];
#pragma unroll
    for (int nt = 0; nt < 4; ++nt) {
        b1f[nt] = zero8;
        if (lhi == 0)
            b1f[nt] = *(const f16x8*)&s_in[(wbase + nt * 16 + lrow) * 8];
    }

#pragma unroll
    for (int mt = 0; mt < 4; ++mt) {
        f16x8 a = zero8;
        if (lhi == 0) a = *(const f16x8*)&w1t[(mt * 16 + lrow) * 8];
        const f32x4 c0 = *(const f32x4*)&fb1[mt * 16 + lhi * 4];
#pragma unroll
        for (int nt = 0; nt < 4; ++nt) {
            f32x4 z = __builtin_amdgcn_mfma_f32_16x16x32_f16(a, b1f[nt], c0, 0, 0, 0);
            const int row = wbase + nt * 16 + lrow;
            union { uint2 u; __half2 h2[2]; } pk;
            pk.h2[0] = __floats2half2_rn(celu_fast(z[0]), celu_fast(z[1]));
            pk.h2[1] = __floats2half2_rn(celu_fast(z[2]), celu_fast(z[3]));
            *(uint2*)hptr(s_h, row, mt * 4 + lhi) = pk.u;
        }
    }

    // wave 0: segment head-scan over sorted dst -> s_start[0..nseg]
    if (tid < 64) {
        u32 base = 0;
        for (int c = 0; c < 4; ++c) {
            const int t = c * 64 + tid;
            const bool head = (t == 0) || (s_d[t] != s_d[t - 1]);
            const u64 m = __ballot(head);
            const u32 pos0 = base + (u32)__popcll(m & ((1ull << tid) - 1ull));
            if (head) s_start[pos0] = (u32)t;
            base += (u32)__popcll(m);
        }
        if (tid == 0) { s_nseg = base; s_start[base] = 256u; }
    }

    // L2 weight fragments + bias (global, L2-cached)
    f16x8 afrag[4][2];
#pragma unroll
    for (int at = 0; at < 4; ++at)
#pragma unroll
        for (int kt = 0; kt < 2; ++kt)
            afrag[at][kt] = *(const f16x8*)(w2t + ((at * 16 + lrow) << 6) + kt * 32 + (lhi << 3));
    f32x4 bias2[4];
#pragma unroll
    for (int at = 0; at < 4; ++at)
        bias2[at] = *(const f32x4*)(fb2 + at * 16 + (lhi << 2));

    __syncthreads();   // s_h (h values) ready

    // ---- layer 2 on MFMA, in-place writeback ----
#pragma unroll
    for (int g = 0; g < 4; ++g) {
        const int rb = wbase + g * 16 + lrow;
        f32x4 acc[4];
#pragma unroll
        for (int at = 0; at < 4; ++at) acc[at] = bias2[at];
#pragma unroll
        for (int kt = 0; kt < 2; ++kt) {
            f16x8 b = *(const f16x8*)hptr(s_h, rb, (kt * 4 + lhi) * 2);
            acc[0] = __builtin_amdgcn_mfma_f32_16x16x32_f16(afrag[0][kt], b, acc[0], 0, 0, 0);
            acc[1] = __builtin_amdgcn_mfma_f32_16x16x32_f16(afrag[1][kt], b, acc[1], 0, 0, 0);
            acc[2] = __builtin_amdgcn_mfma_f32_16x16x32_f16(afrag[2][kt], b, acc[2], 0, 0, 0);
            acc[3] = __builtin_amdgcn_mfma_f32_16x16x32_f16(afrag[3][kt], b, acc[3], 0, 0, 0);
        }
#pragma unroll
        for (int at = 0; at < 4; ++at) {
            union { uint2 u; __half2 h2[2]; } pk;
            pk.h2[0] = __floats2half2_rn(acc[at][0], acc[at][1]);
            pk.h2[1] = __floats2half2_rn(acc[at][2], acc[at][3]);
            *(uint2*)hptr(s_h, rb, at * 4 + lhi) = pk.u;
        }
    }
    __syncthreads();   // messages + segment table ready

    // ---- segmented max-reduce: half-wave per segment, 2 rows/iter ----
    const int hw = tid >> 5;
    const int lane2 = tid & 31;
    const int sub = lane2 >> 4;
    const int c8 = lane2 & 15;
    const u32 nseg = s_nseg;
    for (u32 j = (u32)hw; j < nseg; j += 8) {
        const u32 lo = s_start[j];
        const u32 hi = s_start[j + 1];
        const u32 node = s_d[lo];
        f16x4 m = {};
        for (u32 r0 = lo; r0 < hi; r0 += 2) {
            const u32 r = r0 + (u32)sub;
            if (r < hi) {
                f16x4 v = *(const f16x4*)hptr(s_h, (int)r, c8);
                m = __builtin_elementwise_max(m, v);
            }
        }
        union { f16x4 v; int w2[2]; } a, b;
        a.v = m;
        b.w2[0] = __shfl_down(a.w2[0], 16, 32);
        b.w2[1] = __shfl_down(a.w2[1], 16, 32);
        f16x4 mm = __builtin_elementwise_max(a.v, b.v);
        if (sub == 0) {
            if (lo > 0u && hi < 256u) {
                float4 st;
                st.x = fmaxf((float)mm[0], 0.f);
                st.y = fmaxf((float)mm[1], 0.f);
                st.z = fmaxf((float)mm[2], 0.f);
                st.w = fmaxf((float)mm[3], 0.f);
                *(float4*)((float*)aggr + (size_t)node * 64 + c8 * 4) = st;
            } else {
                u32* arow = aggr + (size_t)node * 64 + c8 * 4;
#pragma unroll
                for (int t = 0; t < 4; ++t) {
                    float f = (float)mm[t];
                    if (f > 0.f) atomicMax(&arow[t], __float_as_uint(f));
                }
            }
        }
    }
}

// ======================= node update MLP on MFMA: 256 threads, 128 nodes =======================
__global__ __launch_bounds__(256) void node_mfma_kernel(
    const float* __restrict__ xp,
    float* io,   // d_out: aggr in, final out
    const __half* __restrict__ g1t, const float* __restrict__ w1x,
    const float* __restrict__ gb1,
    const __half* __restrict__ g2t, const float* __restrict__ gb2)
{
    __shared__ __align__(16) __half s_a[128 * 64];
    __shared__ __align__(16) __half s_u[128 * 64];
    __shared__ __align__(16) float s_x[128 * 4];

    const int tid = threadIdx.x;
    const int n0 = blockIdx.x * 128;

#pragma unroll
    for (int it = 0; it < 8; ++it) {
        const int idx = it * 256 + tid;
        const int row = idx >> 4, c8 = idx & 15;
        const int g = n0 + row;
        float4 v = make_float4(0.f, 0.f, 0.f, 0.f);
        if (g < NN) v = *(const float4*)&io[(size_t)g * 64 + c8 * 4];
        union { uint2 u; __half2 h2[2]; } pk;
        pk.h2[0] = __floats2half2_rn(v.x, v.y);
        pk.h2[1] = __floats2half2_rn(v.z, v.w);
        *(uint2*)hptr(s_a, row, c8) = pk.u;
    }
    if (tid < 128) {
        const int g = n0 + tid;
        float4 a = make_float4(0.f, 0.f, 0.f, 0.f);
        if (g < NN) a = *(const float4*)&xp[(size_t)g * 8];
        *(float4*)&s_x[tid * 4] = a;
    }
    __syncthreads();

    const int l = tid & 63;
    const int wv = tid >> 6;           // 0..3, each wave owns 32 rows
    const int lrow = l & 15;
    const int lhi = l >> 4;

    f16x8 a1[4][2], a2[4][2];
    f32x4 bias1[4], bias2[4];
    f32x4 wx0[4], wx1[4], wx2[4];
#pragma unroll
    for (int at = 0; at < 4; ++at) {
#pragma unroll
        for (int kt = 0; kt < 2; ++kt) {
            const int off = ((at * 16 + lrow) << 6) + kt * 32 + (lhi << 3);
            a1[at][kt] = *(const f16x8*)(g1t + off);
            a2[at][kt] = *(const f16x8*)(g2t + off);
        }
        bias1[at] = *(const f32x4*)&gb1[at * 16 + lhi * 4];
        bias2[at] = *(const f32x4*)&gb2[at * 16 + lhi * 4];
        const int ch = at * 16 + lhi * 4;
        wx0[at] = *(const f32x4*)&w1x[0 * 64 + ch];
        wx1[at] = *(const f32x4*)&w1x[1 * 64 + ch];
        wx2[at] = *(const f32x4*)&w1x[2 * 64 + ch];
    }

#pragma unroll
    for (int g = 0; g < 2; ++g) {
        const int rb = wv * 32 + g * 16 + lrow;
        f32x4 acc[4];
#pragma unroll
        for (int at = 0; at < 4; ++at) acc[at] = bias1[at];
#pragma unroll
        for (int kt = 0; kt < 2; ++kt) {
            f16x8 b = *(const f16x8*)hptr(s_a, rb, (kt * 4 + lhi) * 2);
            acc[0] = __builtin_amdgcn_mfma_f32_16x16x32_f16(a1[0][kt], b, acc[0], 0, 0, 0);
            acc[1] = __builtin_amdgcn_mfma_f32_16x16x32_f16(a1[1][kt], b, acc[1], 0, 0, 0);
            acc[2] = __builtin_amdgcn_mfma_f32_16x16x32_f16(a1[2][kt], b, acc[2], 0, 0, 0);
            acc[3] = __builtin_amdgcn_mfma_f32_16x16x32_f16(a1[3][kt], b, acc[3], 0, 0, 0);
        }
        const float x0 = s_x[rb * 4 + 0];
        const float x1 = s_x[rb * 4 + 1];
        const float x2 = s_x[rb * 4 + 2];
#pragma unroll
        for (int at = 0; at < 4; ++at) {
            f32x4 z = acc[at];
#pragma unroll
            for (int t = 0; t < 4; ++t)
                z[t] = fmaf(x0, wx0[at][t], fmaf(x1, wx1[at][t], fmaf(x2, wx2[at][t], z[t])));
            union { uint2 u; __half2 h2[2]; } pk;
            pk.h2[0] = __floats2half2_rn(celu_fast(z[0]), celu_fast(z[1]));
            pk.h2[1] = __floats2half2_rn(celu_fast(z[2]), celu_fast(z[3]));
            *(uint2*)hptr(s_u, rb, at * 4 + lhi) = pk.u;
        }
    }
    __syncthreads();

#pragma unroll
    for (int g = 0; g < 2; ++g) {
        const int rb = wv * 32 + g * 16 + lrow;
        const int node = n0 + rb;
        f32x4 acc[4];
#pragma unroll
        for (int at = 0; at < 4; ++at) acc[at] = bias2[at];
#pragma unroll
        for (int kt = 0; kt < 2; ++kt) {
            f16x8 b = *(const f16x8*)hptr(s_u, rb, (kt * 4 + lhi) * 2);
            acc[0] = __builtin_amdgcn_mfma_f32_16x16x32_f16(a2[0][kt], b, acc[0], 0, 0, 0);
            acc[1] = __builtin_amdgcn_mfma_f32_16x16x32_f16(a2[1][kt], b, acc[1], 0, 0, 0);
            acc[2] = __builtin_amdgcn_mfma_f32_16x16x32_f16(a2[2][kt], b, acc[2], 0, 0, 0);
            acc[3] = __builtin_amdgcn_mfma_f32_16x16x32_f16(a2[3][kt], b, acc[3], 0, 0, 0);
        }
        if (node < NN) {
#pragma unroll
            for (int at = 0; at < 4; ++at) {
                float4 r;
                r.x = celu_fast(acc[at][0]);
                r.y = celu_fast(acc[at][1]);
                r.z = celu_fast(acc[at][2]);
                r.w = celu_fast(acc[at][3]);
                *(float4*)&io[(size_t)node * 64 + at * 16 + lhi * 4] = r;
            }
        }
    }
}

// ======================= fallback (atomic path) =======================

__global__ __launch_bounds__(256) void zero_kernel(float4* __restrict__ p, int n4) {
    int i = blockIdx.x * blockDim.x + threadIdx.x;
    if (i < n4) p[i] = make_float4(0.f, 0.f, 0.f, 0.f);
}

__global__ __launch_bounds__(256) void edge_atomic_kernel(
    const float* __restrict__ x, const float* __restrict__ pos,
    const int* __restrict__ ei,
    const float* __restrict__ fw1, const float* __restrict__ fb1,
    const float* __restrict__ fw2, const float* __restrict__ fb2,
    unsigned int* __restrict__ aggr)
{
    __shared__ __align__(16) float s_w1[6 * 64];
    __shared__ __align__(16) float s_b1[64];
    __shared__ __align__(16) float s_w2[64 * 64];
    __shared__ __align__(16) float s_b2[64];

    const int tid = threadIdx.x;
    for (int i = tid; i < 6 * 64; i += 256) s_w1[i] = fw1[i];
    for (int i = tid; i < 64 * 64; i += 256) s_w2[i] = fw2[i];
    if (tid < 64) { s_b1[tid] = fb1[tid]; s_b2[tid] = fb2[tid]; }
    __syncthreads();

    const int e = blockIdx.x * 256 + tid;
    if (e >= NE) return;

    const int s = ei[e];
    const int d = ei[NE + e];

    float in[6];
    in[0] = x[s * 3 + 0];
    in[1] = x[s * 3 + 1];
    in[2] = x[s * 3 + 2];
    in[3] = pos[s * 3 + 0] - pos[d * 3 + 0];
    in[4] = pos[s * 3 + 1] - pos[d * 3 + 1];
    in[5] = pos[s * 3 + 2] - pos[d * 3 + 2];

    float h[64];
#pragma unroll
    for (int k = 0; k < 64; k += 4) {
        float4 acc = *(const float4*)&s_b1[k];
#pragma unroll
        for (int q = 0; q < 6; ++q) {
            float4 w = *(const float4*)&s_w1[q * 64 + k];
            acc.x = fmaf(in[q], w.x, acc.x);
            acc.y = fmaf(in[q], w.y, acc.y);
            acc.z = fmaf(in[q], w.z, acc.z);
            acc.w = fmaf(in[q], w.w, acc.w);
        }
        h[k + 0] = celu_fast(acc.x);
        h[k + 1] = celu_fast(acc.y);
        h[k + 2] = celu_fast(acc.z);
        h[k + 3] = celu_fast(acc.w);
    }

    unsigned int* arow = aggr + (size_t)d * 64;
    for (int o = 0; o < 64; o += 4) {
        float4 acc = *(const float4*)&s_b2[o];
#pragma unroll
        for (int k = 0; k < 64; ++k) {
            float4 w = *(const float4*)&s_w2[k * 64 + o];
            acc.x = fmaf(h[k], w.x, acc.x);
            acc.y = fmaf(h[k], w.y, acc.y);
            acc.z = fmaf(h[k], w.z, acc.z);
            acc.w = fmaf(h[k], w.w, acc.w);
        }
        if (acc.x > 0.f) atomicMax(&arow[o + 0], __float_as_uint(acc.x));
        if (acc.y > 0.f) atomicMax(&arow[o + 1], __float_as_uint(acc.y));
        if (acc.z > 0.f) atomicMax(&arow[o + 2], __float_as_uint(acc.z));
        if (acc.w > 0.f) atomicMax(&arow[o + 3], __float_as_uint(acc.w));
    }
}

__global__ __launch_bounds__(256) void node_valu_kernel(
    const float* __restrict__ x,
    float* io,
    const float* __restrict__ gw1, const float* __restrict__ gb1,
    const float* __restrict__ gw2, const float* __restrict__ gb2)
{
    __shared__ __align__(16) float s_w1[67 * 64];
    __shared__ __align__(16) float s_b1[64];
    __shared__ __align__(16) float s_w2[64 * 64];
    __shared__ __align__(16) float s_b2[64];

    const int tid = threadIdx.x;
    for (int i = tid; i < 67 * 64; i += 256) s_w1[i] = gw1[i];
    for (int i = tid; i < 64 * 64; i += 256) s_w2[i] = gw2[i];
    if (tid < 64) { s_b1[tid] = gb1[tid]; s_b2[tid] = gb2[tid]; }
    __syncthreads();

    const int n = blockIdx.x * 256 + tid;
    if (n >= NN) return;

    float a[64];
#pragma unroll
    for (int k = 0; k < 64; k += 4) {
        float4 v = *(const float4*)&io[(size_t)n * 64 + k];
        a[k + 0] = v.x; a[k + 1] = v.y; a[k + 2] = v.z; a[k + 3] = v.w;
    }
    float xv[3];
    xv[0] = x[n * 3 + 0];
    xv[1] = x[n * 3 + 1];
    xv[2] = x[n * 3 + 2];

    float u[64];
    for (int j = 0; j < 64; j += 4) {
        float4 acc = *(const float4*)&s_b1[j];
#pragma unroll
        for (int k = 0; k < 64; ++k) {
            float4 w = *(const float4*)&s_w1[k * 64 + j];
            acc.x = fmaf(a[k], w.x, acc.x);
            acc.y = fmaf(a[k], w.y, acc.y);
            acc.z = fmaf(a[k], w.z, acc.z);
            acc.w = fmaf(a[k], w.w, acc.w);
        }
#pragma unroll
        for (int q = 0; q < 3; ++q) {
            float4 w = *(const float4*)&s_w1[(64 + q) * 64 + j];
            acc.x = fmaf(xv[q], w.x, acc.x);
            acc.y = fmaf(xv[q], w.y, acc.y);
            acc.z = fmaf(xv[q], w.z, acc.z);
            acc.w = fmaf(xv[q], w.w, acc.w);
        }
        u[j + 0] = celu_fast(acc.x);
        u[j + 1] = celu_fast(acc.y);
        u[j + 2] = celu_fast(acc.z);
        u[j + 3] = celu_fast(acc.w);
    }

    float* orow = &io[(size_t)n * 64];
    for (int j = 0; j < 64; j += 4) {
        float4 acc = *(const float4*)&s_b2[j];
#pragma unroll
        for (int k = 0; k < 64; ++k) {
            float4 w = *(const float4*)&s_w2[k * 64 + j];
            acc.x = fmaf(u[k], w.x, acc.x);
            acc.y = fmaf(u[k], w.y, acc.y);
            acc.z = fmaf(u[k], w.z, acc.z);
            acc.w = fmaf(u[k], w.w, acc.w);
        }
        float4 r;
        r.x = celu_fast(acc.x);
        r.y = celu_fast(acc.y);
        r.z = celu_fast(acc.z);
        r.w = celu_fast(acc.w);
        *(float4*)&orow[j] = r;
    }
}

// ======================= launcher =======================

extern "C" void kernel_launch(void* const* d_in, const int* in_sizes, int n_in,
                              void* d_out, int out_size, void* d_ws, size_t ws_size,
                              hipStream_t stream) {
    const float* x   = (const float*)d_in[0];
    const float* pos = (const float*)d_in[1];
    const int*   ei  = (const int*)d_in[2];
    const float* fw1 = (const float*)d_in[3];
    const float* fb1 = (const float*)d_in[4];
    const float* fw2 = (const float*)d_in[5];
    const float* fb2 = (const float*)d_in[6];
    const float* gw1 = (const float*)d_in[7];
    const float* gb1 = (const float*)d_in[8];
    const float* gw2 = (const float*)d_in[9];
    const float* gb2 = (const float*)d_in[10];
    float* out = (float*)d_out;

    const int n4 = NN * 64 / 4;

    auto al = [](size_t v) { return (v + 255) & ~(size_t)255; };
    const size_t o_gcur = 0;
    const size_t o_w1t  = al(o_gcur + (size_t)NBKT * 4);
    const size_t o_w2t  = al(o_w1t + (size_t)64 * 8 * 2);
    const size_t o_g1t  = al(o_w2t + (size_t)64 * 64 * 2);
    const size_t o_g2t  = al(o_g1t + (size_t)64 * 64 * 2);
    const size_t o_w1x  = al(o_g2t + (size_t)64 * 64 * 2);
    const size_t o_xp   = al(o_w1x + (size_t)192 * 4);
    const size_t o_sd1  = al(o_xp + (size_t)NN * 8 * 4);
    const size_t o_sd2  = al(o_sd1 + (size_t)NBKT * BCAP * 4);
    const size_t need   = o_sd2 + (size_t)NE * 4;

    if (ws_size >= need) {
        char* w = (char*)d_ws;
        u32*    gcur = (u32*)(w + o_gcur);
        __half* w1t  = (__half*)(w + o_w1t);
        __half* w2t  = (__half*)(w + o_w2t);
        __half* g1t  = (__half*)(w + o_g1t);
        __half* g2t  = (__half*)(w + o_g2t);
        float*  w1x  = (float*)(w + o_w1x);
        float*  xp   = (float*)(w + o_xp);
        u32*    sd1  = (u32*)(w + o_sd1);
        u32*    sd2  = (u32*)(w + o_sd2);

        (void)hipMemsetAsync(gcur, 0, (size_t)NBKT * 4, stream);
        binA_prep_kernel<<<197, 512, 0, stream>>>(ei, gcur, sd1, (uint4*)out,
                                                  x, pos, xp,
                                                  fw1, fw2, gw1, gw2,
                                                  w1t, w2t, g1t, g2t, w1x);
        sortB_kernel<<<NBKT, 512, 0, stream>>>(sd1, gcur, sd2);
        edge_fused_kernel<<<NE / 256, 256, 0, stream>>>(xp, sd2, w1t, fb1,
                                                        w2t, fb2, (u32*)out);
        node_mfma_kernel<<<(NN + 127) / 128, 256, 0, stream>>>(xp, out, g1t, w1x,
                                                               gb1, g2t, gb2);
    } else {
        // fallback: atomic path (ws too small)
        zero_kernel<<<(n4 + 255) / 256, 256, 0, stream>>>((float4*)out, n4);
        edge_atomic_kernel<<<NE / 256, 256, 0, stream>>>(x, pos, ei, fw1, fb1,
                                                         fw2, fb2, (unsigned int*)out);
        node_valu_kernel<<<(NN + 255) / 256, 256, 0, stream>>>(x, out, gw1, gb1,
                                                               gw2, gb2);
    }
}

// Round 25
// 115.647 us; speedup vs baseline: 1.3077x; 1.0020x over previous
//
#include <hip/hip_runtime.h>
#include <hip/hip_fp16.h>
#include <math.h>

#define NN 50000
#define NE 1600000
#define NBKT 196         // ceil(50000 / 256)
#define BKT_SHIFT 8      // 256 nodes per bucket
#define BCAP 16384       // fixed bucket capacity (mean 8163, sigma ~90)
#define SCAP 12288       // sortB LDS staging capacity (45 sigma above mean)

typedef unsigned int u32;
typedef unsigned long long u64;
typedef _Float16 f16x8 __attribute__((ext_vector_type(8)));
typedef _Float16 f16x4 __attribute__((ext_vector_type(4)));
typedef float f32x4 __attribute__((ext_vector_type(4)));

// fast celu: __expf is the HW v_exp path; abs err ~1e-7, threshold is 1.97e-2
__device__ __forceinline__ float celu_fast(float v) {
    return v > 0.0f ? v : __expf(v) - 1.0f;
}

// swizzled LDS layout for 128B-row f16 tiles: 8B chunks (4 f16),
// chunk c4 of row r -> half-index r*64 + (c4 ^ ((r&7)<<1))*4
__device__ __forceinline__ __half* hptr(__half* base, int row, int c4) {
    return base + (row << 6) + ((c4 ^ ((row & 7) << 1)) << 2);
}

// ======================= binA + prep fused (512 threads) =======================
__global__ __launch_bounds__(512) void binA_prep_kernel(
    const int* __restrict__ ei, u32* __restrict__ gcur, u32* __restrict__ sd1,
    uint4* __restrict__ aggr4,
    const float* __restrict__ x, const float* __restrict__ pos,
    float* __restrict__ xp,
    const float* __restrict__ fw1, const float* __restrict__ fw2,
    const float* __restrict__ gw1, const float* __restrict__ gw2,
    __half* __restrict__ w1t, __half* __restrict__ w2t,
    __half* __restrict__ g1t, __half* __restrict__ g2t,
    float* __restrict__ w1x)
{
    const int tid = threadIdx.x;
    const int b = blockIdx.x;
    if (b == 196) {
        for (int i = tid; i < 4096; i += 512) {
            const int n = i >> 6, k = i & 63;
            w2t[i] = __float2half(fw2[k * 64 + n]);
            g1t[i] = __float2half(gw1[k * 64 + n]);
            g2t[i] = __float2half(gw2[k * 64 + n]);
        }
        if (tid < 512) {
            const int n = tid >> 3, k = tid & 7;
            w1t[tid] = (k < 6) ? __float2half(fw1[k * 64 + n]) : __half(0.0f);
        }
        if (tid < 192) {
            const int c = tid >> 6, ch = tid & 63;
            w1x[tid] = gw1[(64 + c) * 64 + ch];
        }
        return;
    }

    // prep side-work: zero aggr slice + xp build
    for (int idx = b * 512 + tid; idx < NN * 64 / 4; idx += 196 * 512)
        aggr4[idx] = make_uint4(0u, 0u, 0u, 0u);
    {
        const int n = b * 512 + tid;
        if (n < NN) {
            float4 a, p;
            a.x = x[n * 3 + 0]; a.y = x[n * 3 + 1]; a.z = x[n * 3 + 2]; a.w = 0.f;
            p.x = pos[n * 3 + 0]; p.y = pos[n * 3 + 1]; p.z = pos[n * 3 + 2]; p.w = 0.f;
            *(float4*)&xp[n * 8 + 0] = a;
            *(float4*)&xp[n * 8 + 4] = p;
        }
    }

    // bin 8192 edges via LDS staging
    __shared__ u32 s_hist[NBKT];
    __shared__ u32 s_res[NBKT];
    __shared__ u32 s_lofs[NBKT];
    __shared__ u32 s_cur[NBKT];
    __shared__ u32 s_scan[256];
    __shared__ u32 s_stage[8192];   // 32 KiB

    if (tid < NBKT) { s_hist[tid] = 0u; s_cur[tid] = 0u; }
    __syncthreads();

    const int e0 = b * 8192 + tid * 16;
    const bool valid = (e0 < NE);
    u32 ed[16];
    if (valid) {
        const int4* sp = (const int4*)&ei[e0];
        const int4* dp = (const int4*)&ei[NE + e0];
#pragma unroll
        for (int q = 0; q < 4; ++q) {
            int4 s4 = sp[q];
            int4 d4 = dp[q];
            ed[q * 4 + 0] = ((u32)d4.x << 16) | (u32)s4.x;
            ed[q * 4 + 1] = ((u32)d4.y << 16) | (u32)s4.y;
            ed[q * 4 + 2] = ((u32)d4.z << 16) | (u32)s4.z;
            ed[q * 4 + 3] = ((u32)d4.w << 16) | (u32)s4.w;
        }
#pragma unroll
        for (int q = 0; q < 16; ++q)
            atomicAdd(&s_hist[ed[q] >> 24], 1u);
    }
    __syncthreads();
    if (tid < NBKT && s_hist[tid]) s_res[tid] = atomicAdd(&gcur[tid], s_hist[tid]);
    if (tid < 256) s_scan[tid] = (tid < NBKT) ? s_hist[tid] : 0u;
    __syncthreads();
    for (int d = 1; d < 256; d <<= 1) {
        u32 t = 0u;
        if (tid < 256 && tid >= d) t = s_scan[tid - d];
        __syncthreads();
        if (tid < 256) s_scan[tid] += t;
        __syncthreads();
    }
    if (tid < NBKT) s_lofs[tid] = s_scan[tid] - s_hist[tid];
    __syncthreads();
    if (valid) {
#pragma unroll
        for (int q = 0; q < 16; ++q) {
            const u32 bb = ed[q] >> 24;
            const u32 r = atomicAdd(&s_cur[bb], 1u);
            s_stage[s_lofs[bb] + r] = ed[q];
        }
    }
    __syncthreads();
    const int wv = tid >> 6;
    const int lane = tid & 63;
    for (int bk = wv; bk < NBKT; bk += 8) {
        const u32 cnt = s_hist[bk];
        if (!cnt) continue;
        const u32 lo = s_lofs[bk];
        const u32 gres = s_res[bk];
        for (u32 j = (u32)lane; j < cnt; j += 64) {
            const u32 p = gres + j;
            if (p < BCAP) sd1[(u32)bk * BCAP + p] = s_stage[lo + j];
        }
    }
}

// counting sort within each bucket (256 bins), 512 threads, LDS-staged output
__global__ __launch_bounds__(512) void sortB_kernel(const u32* __restrict__ sd1,
                                                    const u32* __restrict__ gcur,
                                                    u32* __restrict__ sd2) {
    __shared__ u32 s_scan[256];
    __shared__ u32 s_cnt[256];
    __shared__ u32 s_pos[256];
    __shared__ u32 s_stage[SCAP];   // 48 KiB
    const int tid = threadIdx.x;
    const int b = blockIdx.x;

    if (tid < 256) s_scan[tid] = (tid < NBKT) ? gcur[tid] : 0u;
    __syncthreads();
    for (int d = 1; d < 256; d <<= 1) {
        u32 t = 0u;
        if (tid < 256 && tid >= d) t = s_scan[tid - d];
        __syncthreads();
        if (tid < 256) s_scan[tid] += t;
        __syncthreads();
    }
    u32 cnt = gcur[b];
    if (cnt > BCAP) cnt = BCAP;
    const u32 outbase = s_scan[b] - cnt;
    const u32 src = (u32)b * BCAP;

    if (tid < 256) s_cnt[tid] = 0u;
    __syncthreads();
    for (u32 j = tid; j < cnt; j += 512)
        atomicAdd(&s_cnt[(sd1[src + j] >> 16) & 255u], 1u);
    __syncthreads();
    if (tid < 256) s_pos[tid] = s_cnt[tid];
    __syncthreads();
    for (int d = 1; d < 256; d <<= 1) {
        u32 t = 0u;
        if (tid < 256 && tid >= d) t = s_pos[tid - d];
        __syncthreads();
        if (tid < 256) s_pos[tid] += t;
        __syncthreads();
    }
    if (tid < 256) s_pos[tid] -= s_cnt[tid];
    __syncthreads();

    if (cnt <= SCAP) {
        for (u32 j = tid; j < cnt; j += 512) {
            const u32 sd = sd1[src + j];
            const u32 dl = (sd >> 16) & 255u;
            const u32 r = atomicAdd(&s_pos[dl], 1u);
            s_stage[r] = sd;
        }
        __syncthreads();
        for (u32 j = tid; j < cnt; j += 512)
            sd2[outbase + j] = s_stage[j];
    } else {
        for (u32 j = tid; j < cnt; j += 512) {
            const u32 sd = sd1[src + j];
            const u32 dl = (sd >> 16) & 255u;
            const u32 r = atomicAdd(&s_pos[dl], 1u);
            sd2[outbase + r] = sd;
        }
    }
}

// ======================= fused edge+gather kernel (best-known R19/R20: 256 thr, 4 waves) =======================
__global__ __launch_bounds__(256, 4) void edge_fused_kernel(
    const float* __restrict__ xp,
    const u32* __restrict__ sdb,
    const __half* __restrict__ w1t, const float* __restrict__ fb1,
    const __half* __restrict__ w2t, const float* __restrict__ fb2,
    u32* __restrict__ aggr)
{
    __shared__ __align__(16) __half s_in[256 * 8];   // 4 KiB
    __shared__ __align__(16) __half s_h[256 * 64];   // 32 KiB, swizzled
    __shared__ u32 s_d[256];
    __shared__ u32 s_start[257];
    __shared__ u32 s_nseg;

    const int tid = threadIdx.x;
    // bijective XCD-chunked swizzle (nwg=6250: q=781, r=2)
    const int xcd = blockIdx.x & 7;
    const int idx = blockIdx.x >> 3;
    const int ebid = (xcd < 2) ? xcd * 782 + idx : 2 * 782 + (xcd - 2) * 781 + idx;

    const int i = ebid * 256 + tid;   // NE % 256 == 0
    const u32 w = sdb[i];
    const int s = (int)(w & 0xFFFFu);
    const int d = (int)(w >> 16);
    s_d[tid] = (u32)d;

    {
        const float4* xp4 = (const float4*)xp;
        float4 axs = xp4[s * 2];       // x0,x1,x2,0
        float4 aps = xp4[s * 2 + 1];   // p0,p1,p2,0
        float4 apd = xp4[d * 2 + 1];
        union { uint4 u; __half2 h2[4]; } pk;
        pk.h2[0] = __floats2half2_rn(axs.x, axs.y);
        pk.h2[1] = __floats2half2_rn(axs.z, aps.x - apd.x);
        pk.h2[2] = __floats2half2_rn(aps.y - apd.y, aps.z - apd.z);
        pk.h2[3] = __floats2half2_rn(0.f, 0.f);
        *(uint4*)&s_in[tid * 8] = pk.u;
    }
    __syncthreads();   // s_in + s_d ready

    const int l = tid & 63;
    const int wbase = tid & 192;   // wave's 64-edge base row
    const int lrow = l & 15;
    const int lhi = l >> 4;

    // ---- layer 1 on MFMA ----
    const f16x8 zero8 = {};
    f16x8 b1f[4];
#pragma unroll
    for (int nt = 0; nt < 4; ++nt) {
        b1f[nt] = zero8;
        if (lhi == 0)
            b1f[nt] = *(const f16x8*)&s_in[(wbase + nt * 16 + lrow) * 8];
    }

#pragma unroll
    for (int mt = 0; mt < 4; ++mt) {
        f16x8 a = zero8;
        if (lhi == 0) a = *(const f16x8*)&w1t[(mt * 16 + lrow) * 8];
        const f32x4 c0 = *(const f32x4*)&fb1[mt * 16 + lhi * 4];
#pragma unroll
        for (int nt = 0; nt < 4; ++nt) {
            f32x4 z = __builtin_amdgcn_mfma_f32_16x16x32_f16(a, b1f[nt], c0, 0, 0, 0);
            const int row = wbase + nt * 16 + lrow;
            union { uint2 u; __half2 h2[2]; } pk;
            pk.h2[0] = __floats2half2_rn(celu_fast(z[0]), celu_fast(z[1]));
            pk.h2[1] = __floats2half2_rn(celu_fast(z[2]), celu_fast(z[3]));
            *(uint2*)hptr(s_h, row, mt * 4 + lhi) = pk.u;
        }
    }

    // wave 0: segment head-scan over sorted dst -> s_start[0..nseg]
    if (tid < 64) {
        u32 base = 0;
        for (int c = 0; c < 4; ++c) {
            const int t = c * 64 + tid;
            const bool head = (t == 0) || (s_d[t] != s_d[t - 1]);
            const u64 m = __ballot(head);
            const u32 pos0 = base + (u32)__popcll(m & ((1ull << tid) - 1ull));
            if (head) s_start[pos0] = (u32)t;
            base += (u32)__popcll(m);
        }
        if (tid == 0) { s_nseg = base; s_start[base] = 256u; }
    }

    // L2 weight fragments + bias (global, L2-cached)
    f16x8 afrag[4][2];
#pragma unroll
    for (int at = 0; at < 4; ++at)
#pragma unroll
        for (int kt = 0; kt < 2; ++kt)
            afrag[at][kt] = *(const f16x8*)(w2t + ((at * 16 + lrow) << 6) + kt * 32 + (lhi << 3));
    f32x4 bias2[4];
#pragma unroll
    for (int at = 0; at < 4; ++at)
        bias2[at] = *(const f32x4*)(fb2 + at * 16 + (lhi << 2));

    __syncthreads();   // s_h (h values) ready

    // ---- layer 2 on MFMA, in-place writeback ----
#pragma unroll
    for (int g = 0; g < 4; ++g) {
        const int rb = wbase + g * 16 + lrow;
        f32x4 acc[4];
#pragma unroll
        for (int at = 0; at < 4; ++at) acc[at] = bias2[at];
#pragma unroll
        for (int kt = 0; kt < 2; ++kt) {
            f16x8 b = *(const f16x8*)hptr(s_h, rb, (kt * 4 + lhi) * 2);
            acc[0] = __builtin_amdgcn_mfma_f32_16x16x32_f16(afrag[0][kt], b, acc[0], 0, 0, 0);
            acc[1] = __builtin_amdgcn_mfma_f32_16x16x32_f16(afrag[1][kt], b, acc[1], 0, 0, 0);
            acc[2] = __builtin_amdgcn_mfma_f32_16x16x32_f16(afrag[2][kt], b, acc[2], 0, 0, 0);
            acc[3] = __builtin_amdgcn_mfma_f32_16x16x32_f16(afrag[3][kt], b, acc[3], 0, 0, 0);
        }
#pragma unroll
        for (int at = 0; at < 4; ++at) {
            union { uint2 u; __half2 h2[2]; } pk;
            pk.h2[0] = __floats2half2_rn(acc[at][0], acc[at][1]);
            pk.h2[1] = __floats2half2_rn(acc[at][2], acc[at][3]);
            *(uint2*)hptr(s_h, rb, at * 4 + lhi) = pk.u;
        }
    }
    __syncthreads();   // messages + segment table ready

    // ---- segmented max-reduce: half-wave per segment, 2 rows/iter ----
    const int hw = tid >> 5;
    const int lane2 = tid & 31;
    const int sub = lane2 >> 4;
    const int c8 = lane2 & 15;
    const u32 nseg = s_nseg;
    for (u32 j = (u32)hw; j < nseg; j += 8) {
        const u32 lo = s_start[j];
        const u32 hi = s_start[j + 1];
        const u32 node = s_d[lo];
        f16x4 m = {};
        for (u32 r0 = lo; r0 < hi; r0 += 2) {
            const u32 r = r0 + (u32)sub;
            if (r < hi) {
                f16x4 v = *(const f16x4*)hptr(s_h, (int)r, c8);
                m = __builtin_elementwise_max(m, v);
            }
        }
        union { f16x4 v; int w2[2]; } a, b;
        a.v = m;
        b.w2[0] = __shfl_down(a.w2[0], 16, 32);
        b.w2[1] = __shfl_down(a.w2[1], 16, 32);
        f16x4 mm = __builtin_elementwise_max(a.v, b.v);
        if (sub == 0) {
            if (lo > 0u && hi < 256u) {
                float4 st;
                st.x = fmaxf((float)mm[0], 0.f);
                st.y = fmaxf((float)mm[1], 0.f);
                st.z = fmaxf((float)mm[2], 0.f);
                st.w = fmaxf((float)mm[3], 0.f);
                *(float4*)((float*)aggr + (size_t)node * 64 + c8 * 4) = st;
            } else {
                u32* arow = aggr + (size_t)node * 64 + c8 * 4;
#pragma unroll
                for (int t = 0; t < 4; ++t) {
                    float f = (float)mm[t];
                    if (f > 0.f) atomicMax(&arow[t], __float_as_uint(f));
                }
            }
        }
    }
}

// ======================= node update MLP on MFMA: 256 threads, 128 nodes =======================
__global__ __launch_bounds__(256) void node_mfma_kernel(
    const float* __restrict__ xp,
    float* io,   // d_out: aggr in, final out
    const __half* __restrict__ g1t, const float* __restrict__ w1x,
    const float* __restrict__ gb1,
    const __half* __restrict__ g2t, const float* __restrict__ gb2)
{
    __shared__ __align__(16) __half s_a[128 * 64];
    __shared__ __align__(16) __half s_u[128 * 64];
    __shared__ __align__(16) float s_x[128 * 4];

    const int tid = threadIdx.x;
    const int n0 = blockIdx.x * 128;

#pragma unroll
    for (int it = 0; it < 8; ++it) {
        const int idx = it * 256 + tid;
        const int row = idx >> 4, c8 = idx & 15;
        const int g = n0 + row;
        float4 v = make_float4(0.f, 0.f, 0.f, 0.f);
        if (g < NN) v = *(const float4*)&io[(size_t)g * 64 + c8 * 4];
        union { uint2 u; __half2 h2[2]; } pk;
        pk.h2[0] = __floats2half2_rn(v.x, v.y);
        pk.h2[1] = __floats2half2_rn(v.z, v.w);
        *(uint2*)hptr(s_a, row, c8) = pk.u;
    }
    if (tid < 128) {
        const int g = n0 + tid;
        float4 a = make_float4(0.f, 0.f, 0.f, 0.f);
        if (g < NN) a = *(const float4*)&xp[(size_t)g * 8];
        *(float4*)&s_x[tid * 4] = a;
    }
    __syncthreads();

    const int l = tid & 63;
    const int wv = tid >> 6;           // 0..3, each wave owns 32 rows
    const int lrow = l & 15;
    const int lhi = l >> 4;

    f16x8 a1[4][2], a2[4][2];
    f32x4 bias1[4], bias2[4];
    f32x4 wx0[4], wx1[4], wx2[4];
#pragma unroll
    for (int at = 0; at < 4; ++at) {
#pragma unroll
        for (int kt = 0; kt < 2; ++kt) {
            const int off = ((at * 16 + lrow) << 6) + kt * 32 + (lhi << 3);
            a1[at][kt] = *(const f16x8*)(g1t + off);
            a2[at][kt] = *(const f16x8*)(g2t + off);
        }
        bias1[at] = *(const f32x4*)&gb1[at * 16 + lhi * 4];
        bias2[at] = *(const f32x4*)&gb2[at * 16 + lhi * 4];
        const int ch = at * 16 + lhi * 4;
        wx0[at] = *(const f32x4*)&w1x[0 * 64 + ch];
        wx1[at] = *(const f32x4*)&w1x[1 * 64 + ch];
        wx2[at] = *(const f32x4*)&w1x[2 * 64 + ch];
    }

#pragma unroll
    for (int g = 0; g < 2; ++g) {
        const int rb = wv * 32 + g * 16 + lrow;
        f32x4 acc[4];
#pragma unroll
        for (int at = 0; at < 4; ++at) acc[at] = bias1[at];
#pragma unroll
        for (int kt = 0; kt < 2; ++kt) {
            f16x8 b = *(const f16x8*)hptr(s_a, rb, (kt * 4 + lhi) * 2);
            acc[0] = __builtin_amdgcn_mfma_f32_16x16x32_f16(a1[0][kt], b, acc[0], 0, 0, 0);
            acc[1] = __builtin_amdgcn_mfma_f32_16x16x32_f16(a1[1][kt], b, acc[1], 0, 0, 0);
            acc[2] = __builtin_amdgcn_mfma_f32_16x16x32_f16(a1[2][kt], b, acc[2], 0, 0, 0);
            acc[3] = __builtin_amdgcn_mfma_f32_16x16x32_f16(a1[3][kt], b, acc[3], 0, 0, 0);
        }
        const float x0 = s_x[rb * 4 + 0];
        const float x1 = s_x[rb * 4 + 1];
        const float x2 = s_x[rb * 4 + 2];
#pragma unroll
        for (int at = 0; at < 4; ++at) {
            f32x4 z = acc[at];
#pragma unroll
            for (int t = 0; t < 4; ++t)
                z[t] = fmaf(x0, wx0[at][t], fmaf(x1, wx1[at][t], fmaf(x2, wx2[at][t], z[t])));
            union { uint2 u; __half2 h2[2]; } pk;
            pk.h2[0] = __floats2half2_rn(celu_fast(z[0]), celu_fast(z[1]));
            pk.h2[1] = __floats2half2_rn(celu_fast(z[2]), celu_fast(z[3]));
            *(uint2*)hptr(s_u, rb, at * 4 + lhi) = pk.u;
        }
    }
    __syncthreads();

#pragma unroll
    for (int g = 0; g < 2; ++g) {
        const int rb = wv * 32 + g * 16 + lrow;
        const int node = n0 + rb;
        f32x4 acc[4];
#pragma unroll
        for (int at = 0; at < 4; ++at) acc[at] = bias2[at];
#pragma unroll
        for (int kt = 0; kt < 2; ++kt) {
            f16x8 b = *(const f16x8*)hptr(s_u, rb, (kt * 4 + lhi) * 2);
            acc[0] = __builtin_amdgcn_mfma_f32_16x16x32_f16(a2[0][kt], b, acc[0], 0, 0, 0);
            acc[1] = __builtin_amdgcn_mfma_f32_16x16x32_f16(a2[1][kt], b, acc[1], 0, 0, 0);
            acc[2] = __builtin_amdgcn_mfma_f32_16x16x32_f16(a2[2][kt], b, acc[2], 0, 0, 0);
            acc[3] = __builtin_amdgcn_mfma_f32_16x16x32_f16(a2[3][kt], b, acc[3], 0, 0, 0);
        }
        if (node < NN) {
#pragma unroll
            for (int at = 0; at < 4; ++at) {
                float4 r;
                r.x = celu_fast(acc[at][0]);
                r.y = celu_fast(acc[at][1]);
                r.z = celu_fast(acc[at][2]);
                r.w = celu_fast(acc[at][3]);
                *(float4*)&io[(size_t)node * 64 + at * 16 + lhi * 4] = r;
            }
        }
    }
}

// ======================= fallback (atomic path) =======================

__global__ __launch_bounds__(256) void zero_kernel(float4* __restrict__ p, int n4) {
    int i = blockIdx.x * blockDim.x + threadIdx.x;
    if (i < n4) p[i] = make_float4(0.f, 0.f, 0.f, 0.f);
}

__global__ __launch_bounds__(256) void edge_atomic_kernel(
    const float* __restrict__ x, const float* __restrict__ pos,
    const int* __restrict__ ei,
    const float* __restrict__ fw1, const float* __restrict__ fb1,
    const float* __restrict__ fw2, const float* __restrict__ fb2,
    unsigned int* __restrict__ aggr)
{
    __shared__ __align__(16) float s_w1[6 * 64];
    __shared__ __align__(16) float s_b1[64];
    __shared__ __align__(16) float s_w2[64 * 64];
    __shared__ __align__(16) float s_b2[64];

    const int tid = threadIdx.x;
    for (int i = tid; i < 6 * 64; i += 256) s_w1[i] = fw1[i];
    for (int i = tid; i < 64 * 64; i += 256) s_w2[i] = fw2[i];
    if (tid < 64) { s_b1[tid] = fb1[tid]; s_b2[tid] = fb2[tid]; }
    __syncthreads();

    const int e = blockIdx.x * 256 + tid;
    if (e >= NE) return;

    const int s = ei[e];
    const int d = ei[NE + e];

    float in[6];
    in[0] = x[s * 3 + 0];
    in[1] = x[s * 3 + 1];
    in[2] = x[s * 3 + 2];
    in[3] = pos[s * 3 + 0] - pos[d * 3 + 0];
    in[4] = pos[s * 3 + 1] - pos[d * 3 + 1];
    in[5] = pos[s * 3 + 2] - pos[d * 3 + 2];

    float h[64];
#pragma unroll
    for (int k = 0; k < 64; k += 4) {
        float4 acc = *(const float4*)&s_b1[k];
#pragma unroll
        for (int q = 0; q < 6; ++q) {
            float4 w = *(const float4*)&s_w1[q * 64 + k];
            acc.x = fmaf(in[q], w.x, acc.x);
            acc.y = fmaf(in[q], w.y, acc.y);
            acc.z = fmaf(in[q], w.z, acc.z);
            acc.w = fmaf(in[q], w.w, acc.w);
        }
        h[k + 0] = celu_fast(acc.x);
        h[k + 1] = celu_fast(acc.y);
        h[k + 2] = celu_fast(acc.z);
        h[k + 3] = celu_fast(acc.w);
    }

    unsigned int* arow = aggr + (size_t)d * 64;
    for (int o = 0; o < 64; o += 4) {
        float4 acc = *(const float4*)&s_b2[o];
#pragma unroll
        for (int k = 0; k < 64; ++k) {
            float4 w = *(const float4*)&s_w2[k * 64 + o];
            acc.x = fmaf(h[k], w.x, acc.x);
            acc.y = fmaf(h[k], w.y, acc.y);
            acc.z = fmaf(h[k], w.z, acc.z);
            acc.w = fmaf(h[k], w.w, acc.w);
        }
        if (acc.x > 0.f) atomicMax(&arow[o + 0], __float_as_uint(acc.x));
        if (acc.y > 0.f) atomicMax(&arow[o + 1], __float_as_uint(acc.y));
        if (acc.z > 0.f) atomicMax(&arow[o + 2], __float_as_uint(acc.z));
        if (acc.w > 0.f) atomicMax(&arow[o + 3], __float_as_uint(acc.w));
    }
}

__global__ __launch_bounds__(256) void node_valu_kernel(
    const float* __restrict__ x,
    float* io,
    const float* __restrict__ gw1, const float* __restrict__ gb1,
    const float* __restrict__ gw2, const float* __restrict__ gb2)
{
    __shared__ __align__(16) float s_w1[67 * 64];
    __shared__ __align__(16) float s_b1[64];
    __shared__ __align__(16) float s_w2[64 * 64];
    __shared__ __align__(16) float s_b2[64];

    const int tid = threadIdx.x;
    for (int i = tid; i < 67 * 64; i += 256) s_w1[i] = gw1[i];
    for (int i = tid; i < 64 * 64; i += 256) s_w2[i] = gw2[i];
    if (tid < 64) { s_b1[tid] = gb1[tid]; s_b2[tid] = gb2[tid]; }
    __syncthreads();

    const int n = blockIdx.x * 256 + tid;
    if (n >= NN) return;

    float a[64];
#pragma unroll
    for (int k = 0; k < 64; k += 4) {
        float4 v = *(const float4*)&io[(size_t)n * 64 + k];
        a[k + 0] = v.x; a[k + 1] = v.y; a[k + 2] = v.z; a[k + 3] = v.w;
    }
    float xv[3];
    xv[0] = x[n * 3 + 0];
    xv[1] = x[n * 3 + 1];
    xv[2] = x[n * 3 + 2];

    float u[64];
    for (int j = 0; j < 64; j += 4) {
        float4 acc = *(const float4*)&s_b1[j];
#pragma unroll
        for (int k = 0; k < 64; ++k) {
            float4 w = *(const float4*)&s_w1[k * 64 + j];
            acc.x = fmaf(a[k], w.x, acc.x);
            acc.y = fmaf(a[k], w.y, acc.y);
            acc.z = fmaf(a[k], w.z, acc.z);
            acc.w = fmaf(a[k], w.w, acc.w);
        }
#pragma unroll
        for (int q = 0; q < 3; ++q) {
            float4 w = *(const float4*)&s_w1[(64 + q) * 64 + j];
            acc.x = fmaf(xv[q], w.x, acc.x);
            acc.y = fmaf(xv[q], w.y, acc.y);
            acc.z = fmaf(xv[q], w.z, acc.z);
            acc.w = fmaf(xv[q], w.w, acc.w);
        }
        u[j + 0] = celu_fast(acc.x);
        u[j + 1] = celu_fast(acc.y);
        u[j + 2] = celu_fast(acc.z);
        u[j + 3] = celu_fast(acc.w);
    }

    float* orow = &io[(size_t)n * 64];
    for (int j = 0; j < 64; j += 4) {
        float4 acc = *(const float4*)&s_b2[j];
#pragma unroll
        for (int k = 0; k < 64; ++k) {
            float4 w = *(const float4*)&s_w2[k * 64 + j];
            acc.x = fmaf(u[k], w.x, acc.x);
            acc.y = fmaf(u[k], w.y, acc.y);
            acc.z = fmaf(u[k], w.z, acc.z);
            acc.w = fmaf(u[k], w.w, acc.w);
        }
        float4 r;
        r.x = celu_fast(acc.x);
        r.y = celu_fast(acc.y);
        r.z = celu_fast(acc.z);
        r.w = celu_fast(acc.w);
        *(float4*)&orow[j] = r;
    }
}

// ======================= launcher =======================

extern "C" void kernel_launch(void* const* d_in, const int* in_sizes, int n_in,
                              void* d_out, int out_size, void* d_ws, size_t ws_size,
                              hipStream_t stream) {
    const float* x   = (const float*)d_in[0];
    const float* pos = (const float*)d_in[1];
    const int*   ei  = (const int*)d_in[2];
    const float* fw1 = (const float*)d_in[3];
    const float* fb1 = (const float*)d_in[4];
    const float* fw2 = (const float*)d_in[5];
    const float* fb2 = (const float*)d_in[6];
    const float* gw1 = (const float*)d_in[7];
    const float* gb1 = (const float*)d_in[8];
    const float* gw2 = (const float*)d_in[9];
    const float* gb2 = (const float*)d_in[10];
    float* out = (float*)d_out;

    const int n4 = NN * 64 / 4;

    auto al = [](size_t v) { return (v + 255) & ~(size_t)255; };
    const size_t o_gcur = 0;
    const size_t o_w1t  = al(o_gcur + (size_t)NBKT * 4);
    const size_t o_w2t  = al(o_w1t + (size_t)64 * 8 * 2);
    const size_t o_g1t  = al(o_w2t + (size_t)64 * 64 * 2);
    const size_t o_g2t  = al(o_g1t + (size_t)64 * 64 * 2);
    const size_t o_w1x  = al(o_g2t + (size_t)64 * 64 * 2);
    const size_t o_xp   = al(o_w1x + (size_t)192 * 4);
    const size_t o_sd1  = al(o_xp + (size_t)NN * 8 * 4);
    const size_t o_sd2  = al(o_sd1 + (size_t)NBKT * BCAP * 4);
    const size_t need   = o_sd2 + (size_t)NE * 4;

    if (ws_size >= need) {
        char* w = (char*)d_ws;
        u32*    gcur = (u32*)(w + o_gcur);
        __half* w1t  = (__half*)(w + o_w1t);
        __half* w2t  = (__half*)(w + o_w2t);
        __half* g1t  = (__half*)(w + o_g1t);
        __half* g2t  = (__half*)(w + o_g2t);
        float*  w1x  = (float*)(w + o_w1x);
        float*  xp   = (float*)(w + o_xp);
        u32*    sd1  = (u32*)(w + o_sd1);
        u32*    sd2  = (u32*)(w + o_sd2);

        (void)hipMemsetAsync(gcur, 0, (size_t)NBKT * 4, stream);
        binA_prep_kernel<<<197, 512, 0, stream>>>(ei, gcur, sd1, (uint4*)out,
                                                  x, pos, xp,
                                                  fw1, fw2, gw1, gw2,
                                                  w1t, w2t, g1t, g2t, w1x);
        sortB_kernel<<<NBKT, 512, 0, stream>>>(sd1, gcur, sd2);
        edge_fused_kernel<<<NE / 256, 256, 0, stream>>>(xp, sd2, w1t, fb1,
                                                        w2t, fb2, (u32*)out);
        node_mfma_kernel<<<(NN + 127) / 128, 256, 0, stream>>>(xp, out, g1t, w1x,
                                                               gb1, g2t, gb2);
    } else {
        // fallback: atomic path (ws too small)
        zero_kernel<<<(n4 + 255) / 256, 256, 0, stream>>>((float4*)out, n4);
        edge_atomic_kernel<<<NE / 256, 256, 0, stream>>>(x, pos, ei, fw1, fb1,
                                                         fw2, fb2, (unsigned int*)out);
        node_valu_kernel<<<(NN + 255) / 256, 256, 0, stream>>>(x, out, gw1, gb1,
                                                               gw2, gb2);
    }
}